// Round 4
// baseline (733.018 us; speedup 1.0000x reference)
//
#include <hip/hip_runtime.h>
#include <hip/hip_bf16.h>
#include <math.h>
#include <stdint.h>
#include <stddef.h>

// ---------------------------------------------------------------------------
// MetaEvidentialGSL: N=8192, D=768, H1=512, H2=256
//  1. split X into bf16 hi/lo; transpose+convert weights to bf16
//  2. head1 via split-bf16 MFMA GEMMs -> m0,v0,a0,b0 + gate G
//  3. QKV = X @ [Wq|Wk|Wg] (one bf16 GEMM); V transposed
//  4. attention in 2 panels of 4096: Wp = exp(QK^T/sqrt(D))*G_j (bf16) with
//     row-sum atomics E/T; Macc = / += Wp @ V (fp32)
//  5. Y = X + gelu(alpha*Macc + bg), alpha = G/(E*max(G*T/E,1e-8))
//  6. head2 on Y -> mu,v,al,be
// R2: XOR swizzle killed bank conflicts (3.5M -> 0).
// R3: BK=64/PANEL=4096 — neutral; counters showed latency-bound (all pipes
//     <27% busy, block-iter slot 2925 cyc vs 770 cyc max pipe demand).
// R4: double-buffered LDS ping-pong, raw `s_waitcnt vmcnt(L); s_barrier` asm
//     so the global->LDS DMA for iter k+1 overlaps compute of iter k (the
//     compiler's __syncthreads always drains vmcnt(0) — this bypasses it).
//     BK=32 so 2 buffers stay within 32KB LDS (no residency loss).
// ---------------------------------------------------------------------------

#define NT    8192
#define DD    768
#define DH1   512
#define DH2   256
#define PANEL 4096
#define NPAN  (NT / PANEL)

typedef __attribute__((ext_vector_type(8))) short  short8;
typedef __attribute__((ext_vector_type(4))) float  f32x4;

#define MFMA16(a, b, c) __builtin_amdgcn_mfma_f32_16x16x32_bf16((a), (b), (c), 0, 0, 0)

__device__ __forceinline__ float bf2f(__hip_bfloat16 x) { return __bfloat162float(x); }
__device__ __forceinline__ __hip_bfloat16 f2bf(float x) { return __float2bfloat16(x); }

__device__ __forceinline__ float gelu_f(float x) {
    return 0.5f * x * (1.0f + erff(x * 0.7071067811865476f));
}
__device__ __forceinline__ float softplus_f(float x) {
    return (x > 20.0f) ? x : log1pf(expf(x));
}

// async 16B/lane global->LDS. LDS dest must be wave-uniform base + lane*16.
__device__ __forceinline__ void gload16(const __hip_bfloat16* g, __hip_bfloat16* l) {
    __builtin_amdgcn_global_load_lds(
        (const __attribute__((address_space(1))) void*)(const void*)g,
        (__attribute__((address_space(3))) void*)(void*)l,
        16, 0, 0);
}

// wait until <=N vm ops outstanding, then barrier. N = loads just issued for
// the NEXT buffer; everything older (the buffer we're about to read) is done.
template <int N>
__device__ __forceinline__ void wait_barrier() {
    asm volatile("s_waitcnt vmcnt(%0)\n\ts_barrier" :: "i"(N) : "memory");
}
__device__ __forceinline__ void plain_barrier() {
    asm volatile("s_barrier" ::: "memory");
}

// ---------------------------------------------------------------------------
// GEMM: C(MxN) = A(MxK) @ Bt(NxK)^T. Tile TM x TN, BK=32, 4 waves, 256 thr.
// Double-buffered LDS; R2's proven-zero-conflict XOR chunk swizzle:
// 16B chunk c of row r stored at slot c ^ ((r>>1)&3).
// SPLIT: A,B given as hi+lo bf16 pairs; computes hi*hi + hi*lo + lo*hi.
// EPI: 0 = store bf16; 1 = bias+gelu -> split bf16 (hi/lo)
//      2 = w=exp(acc/sqrt(D))*G[col] -> bf16, atomic rowsum E (exp) / T (w)
//      3 = fp32 store (accin=0) or accumulate (accin=1)
// ---------------------------------------------------------------------------
template <int EPI, bool SPLIT, int TM, int TN>
__global__ __launch_bounds__(256)
void gemm_bt(const __hip_bfloat16* __restrict__ Ahi, const __hip_bfloat16* __restrict__ Alo, int lda,
             const __hip_bfloat16* __restrict__ Bhi, const __hip_bfloat16* __restrict__ Blo, int ldb,
             __hip_bfloat16* __restrict__ obf_hi, __hip_bfloat16* __restrict__ obf_lo,
             float* __restrict__ ofp, int ldc,
             const float* __restrict__ bias, const float* __restrict__ Gv,
             float* __restrict__ Esum, float* __restrict__ Tsum, int K, int accin)
{
    constexpr int NB  = SPLIT ? 2 : 1;
    constexpr int WRM = (TM == 128 && TN == 128) ? 2 : (TM == 128 ? 4 : 2);
    constexpr int WCN = 4 / WRM;
    constexpr int WTM = TM / WRM;
    constexpr int WTN = TN / WCN;
    constexpr int MI  = WTM / 16;
    constexpr int NI  = WTN / 16;
    constexpr int PA  = TM / 64;          // staging passes (64 rows x 64 B)
    constexpr int PB  = TN / 64;
    constexpr int LPI = (PA + PB) * NB;   // DMA loads per thread per iter

    __shared__ __align__(16) __hip_bfloat16 As[NB][2][TM * 32];
    __shared__ __align__(16) __hip_bfloat16 Bs[NB][2][TN * 32];

    const int tid  = threadIdx.x;
    const int wave = tid >> 6;
    const int lane = tid & 63;
    const int tm = blockIdx.y * TM;
    const int tn = blockIdx.x * TN;

    // staging: thread stages one 16B chunk: row = tid>>2, chunk = tid&3.
    // LDS slot (tid&3) receives global chunk (tid&3)^((srow>>1)&3).
    const int srow  = tid >> 2;
    const int sgcol = ((tid & 3) ^ ((srow >> 1) & 3)) * 8;
    const int lofs  = srow * 32 + (tid & 3) * 8;

    size_t aoffs[PA], boffs[PB];
#pragma unroll
    for (int p = 0; p < PA; ++p) aoffs[p] = (size_t)(tm + p * 64 + srow) * lda + sgcol;
#pragma unroll
    for (int p = 0; p < PB; ++p) boffs[p] = (size_t)(tn + p * 64 + srow) * ldb + sgcol;

    auto stage = [&](int k0, int buf) {
#pragma unroll
        for (int p = 0; p < PA; ++p)
            gload16(Ahi + aoffs[p] + k0, &As[0][buf][p * 2048 + lofs]);
#pragma unroll
        for (int p = 0; p < PB; ++p)
            gload16(Bhi + boffs[p] + k0, &Bs[0][buf][p * 2048 + lofs]);
        if constexpr (SPLIT) {
#pragma unroll
            for (int p = 0; p < PA; ++p)
                gload16(Alo + aoffs[p] + k0, &As[1][buf][p * 2048 + lofs]);
#pragma unroll
            for (int p = 0; p < PB; ++p)
                gload16(Blo + boffs[p] + k0, &Bs[1][buf][p * 2048 + lofs]);
        }
    };

    f32x4 acc[MI][NI];
#pragma unroll
    for (int i = 0; i < MI; ++i)
#pragma unroll
        for (int j = 0; j < NI; ++j) {
            f32x4 z = {0.0f, 0.0f, 0.0f, 0.0f};
            acc[i][j] = z;
        }

    const int wm   = (wave / WCN) * WTM;
    const int wn   = (wave % WCN) * WTN;
    const int l16  = lane & 15;
    const int quad = lane >> 4;
    const int rchunk = (quad ^ ((l16 >> 1) & 3)) * 8;   // read-side swizzle
    const int arow0  = (wm + l16) * 32 + rchunk;
    const int brow0  = (wn + l16) * 32 + rchunk;

    const int nIter = K >> 5;
    stage(0, 0);
    for (int k = 0; k < nIter; ++k) {
        const int cb = k & 1;
        if (k + 1 < nIter) {
            stage((k + 1) << 5, cb ^ 1);
            wait_barrier<LPI>();   // prev-buffer loads landed; next-buffer in flight
        } else {
            wait_barrier<0>();
        }

        short8 ah[MI], bh[NI];
#pragma unroll
        for (int i = 0; i < MI; ++i) ah[i] = *(const short8*)&As[0][cb][arow0 + i * 512];
#pragma unroll
        for (int j = 0; j < NI; ++j) bh[j] = *(const short8*)&Bs[0][cb][brow0 + j * 512];
        if constexpr (SPLIT) {
            short8 al[MI], bl[NI];
#pragma unroll
            for (int i = 0; i < MI; ++i) al[i] = *(const short8*)&As[1][cb][arow0 + i * 512];
#pragma unroll
            for (int j = 0; j < NI; ++j) bl[j] = *(const short8*)&Bs[1][cb][brow0 + j * 512];
#pragma unroll
            for (int mi = 0; mi < MI; ++mi)
#pragma unroll
                for (int ni = 0; ni < NI; ++ni) {
                    acc[mi][ni] = MFMA16(ah[mi], bh[ni], acc[mi][ni]);
                    acc[mi][ni] = MFMA16(ah[mi], bl[ni], acc[mi][ni]);
                    acc[mi][ni] = MFMA16(al[mi], bh[ni], acc[mi][ni]);
                }
        } else {
#pragma unroll
            for (int mi = 0; mi < MI; ++mi)
#pragma unroll
                for (int ni = 0; ni < NI; ++ni)
                    acc[mi][ni] = MFMA16(ah[mi], bh[ni], acc[mi][ni]);
        }
        plain_barrier();   // all waves done reading buf cb before it's restaged
    }

    // C/D layout: col = lane&15, row = (lane>>4)*4 + reg  [verified m89/m91]
    const int rbase = tm + wm + quad * 4;
    const int cbase = tn + wn + l16;

    if constexpr (EPI == 0) {
#pragma unroll
        for (int mi = 0; mi < MI; ++mi)
#pragma unroll
            for (int ni = 0; ni < NI; ++ni) {
                f32x4 v = acc[mi][ni];
                const int col = cbase + ni * 16;
#pragma unroll
                for (int r = 0; r < 4; ++r)
                    obf_hi[(size_t)(rbase + mi * 16 + r) * ldc + col] = f2bf(v[r]);
            }
    } else if constexpr (EPI == 1) {
#pragma unroll
        for (int mi = 0; mi < MI; ++mi)
#pragma unroll
            for (int ni = 0; ni < NI; ++ni) {
                f32x4 v = acc[mi][ni];
                const int col = cbase + ni * 16;
                const float b = bias[col];
#pragma unroll
                for (int r = 0; r < 4; ++r) {
                    float g = gelu_f(v[r] + b);
                    __hip_bfloat16 h = f2bf(g);
                    size_t idx = (size_t)(rbase + mi * 16 + r) * ldc + col;
                    obf_hi[idx] = h;
                    obf_lo[idx] = f2bf(g - bf2f(h));
                }
            }
    } else if constexpr (EPI == 2) {
        const float SCL = 0.03608439182435161f;   // 1/sqrt(768)
#pragma unroll
        for (int mi = 0; mi < MI; ++mi) {
            float sE[4] = {0.f, 0.f, 0.f, 0.f};
            float sT[4] = {0.f, 0.f, 0.f, 0.f};
#pragma unroll
            for (int ni = 0; ni < NI; ++ni) {
                f32x4 v = acc[mi][ni];
                const int col = cbase + ni * 16;
                const float g = Gv[col];
#pragma unroll
                for (int r = 0; r < 4; ++r) {
                    float we = __expf(v[r] * SCL);
                    float w  = we * g;
                    obf_hi[(size_t)(rbase + mi * 16 + r) * ldc + col] = f2bf(w);
                    sE[r] += we;
                    sT[r] += w;
                }
            }
#pragma unroll
            for (int st = 1; st < 16; st <<= 1)
#pragma unroll
                for (int r = 0; r < 4; ++r) {
                    sE[r] += __shfl_xor(sE[r], st);
                    sT[r] += __shfl_xor(sT[r], st);
                }
            if (l16 == 0) {
#pragma unroll
                for (int r = 0; r < 4; ++r) {
                    atomicAdd(&Esum[rbase + mi * 16 + r], sE[r]);
                    atomicAdd(&Tsum[rbase + mi * 16 + r], sT[r]);
                }
            }
        }
    } else {  // EPI == 3: fp32 store / accumulate
#pragma unroll
        for (int mi = 0; mi < MI; ++mi)
#pragma unroll
            for (int ni = 0; ni < NI; ++ni) {
                f32x4 v = acc[mi][ni];
                const int col = cbase + ni * 16;
#pragma unroll
                for (int r = 0; r < 4; ++r) {
                    size_t idx = (size_t)(rbase + mi * 16 + r) * ldc + col;
                    if (accin) ofp[idx] += v[r];
                    else       ofp[idx]  = v[r];
                }
            }
    }
}

// ---------------------------------------------------------------------------
// transpose f32 (RxC) -> bf16 (CxR), optional lo residual output
// ---------------------------------------------------------------------------
__global__ __launch_bounds__(256)
void transpose_f2b(const float* __restrict__ in, int ldin,
                   __hip_bfloat16* __restrict__ ohi, __hip_bfloat16* __restrict__ olo, int ldout)
{
    __shared__ float t[32][33];
    const int tx = threadIdx.x & 31;
    const int ty = threadIdx.x >> 5;
    const int r0 = blockIdx.y * 32;
    const int c0 = blockIdx.x * 32;
#pragma unroll
    for (int j = 0; j < 32; j += 8)
        t[ty + j][tx] = in[(size_t)(r0 + ty + j) * ldin + c0 + tx];
    __syncthreads();
#pragma unroll
    for (int j = 0; j < 32; j += 8) {
        float x = t[tx][ty + j];
        __hip_bfloat16 h = f2bf(x);
        size_t o = (size_t)(c0 + ty + j) * ldout + r0 + tx;
        ohi[o] = h;
        if (olo) olo[o] = f2bf(x - bf2f(h));
    }
}

__global__ __launch_bounds__(256)
void transpose_b2b(const __hip_bfloat16* __restrict__ in, int ldin,
                   __hip_bfloat16* __restrict__ out, int ldout)
{
    __shared__ __hip_bfloat16 t[32][33];
    const int tx = threadIdx.x & 31;
    const int ty = threadIdx.x >> 5;
    const int r0 = blockIdx.y * 32;
    const int c0 = blockIdx.x * 32;
#pragma unroll
    for (int j = 0; j < 32; j += 8)
        t[ty + j][tx] = in[(size_t)(r0 + ty + j) * ldin + c0 + tx];
    __syncthreads();
#pragma unroll
    for (int j = 0; j < 32; j += 8)
        out[(size_t)(c0 + ty + j) * ldout + r0 + tx] = t[tx][ty + j];
}

__global__ __launch_bounds__(256)
void cvt_split(const float* __restrict__ in, __hip_bfloat16* __restrict__ hi,
               __hip_bfloat16* __restrict__ lo)
{
    const int i = (blockIdx.x * 256 + threadIdx.x) * 4;
    f32x4 v = *(const f32x4*)(in + i);
#pragma unroll
    for (int k = 0; k < 4; ++k) {
        __hip_bfloat16 h = f2bf(v[k]);
        hi[i + k] = h;
        lo[i + k] = f2bf(v[k] - bf2f(h));
    }
}

// ---------------------------------------------------------------------------
// head tail: r = H2 @ Wh + bh (fp32, hi+lo input), NIG transforms, optional G.
// ---------------------------------------------------------------------------
__global__ __launch_bounds__(256)
void head_tail(const __hip_bfloat16* __restrict__ H2hi, const __hip_bfloat16* __restrict__ H2lo,
               const float* __restrict__ Wh, const float* __restrict__ bh,
               const float* __restrict__ gamp,
               float* __restrict__ outBase, float* __restrict__ Gout)
{
    __shared__ float sa[64], sb[64];
    const int tid = threadIdx.x;
    const int rl  = tid >> 2;
    const int c   = tid & 3;
    const int row = blockIdx.x * 64 + rl;
    const __hip_bfloat16* hh = H2hi + (size_t)row * DH2;
    const __hip_bfloat16* hl = H2lo + (size_t)row * DH2;
    float acc = bh[c];
    for (int k = 0; k < DH2; ++k) {
        float h = bf2f(hh[k]) + bf2f(hl[k]);
        acc = fmaf(h, Wh[k * 4 + c], acc);
    }
    float sp = softplus_f(acc);
    if (c == 0) {
        outBase[row] = acc;                        // mu
    } else if (c == 1) {
        outBase[NT + row] = sp + 1e-6f;            // v
    } else if (c == 2) {
        float a0 = (sp + 1.0f) + 1e-6f;            // match ref assoc order
        outBase[2 * NT + row] = a0;
        if (Gout) sa[rl] = a0 - 1.0f;              // match ref's a0-1 rounding
    } else {
        float b0 = sp + 1e-6f;
        outBase[3 * NT + row] = b0;
        if (Gout) sb[rl] = b0;
    }
    if (Gout != nullptr) {
        __syncthreads();
        if (c == 0) {
            float u   = sb[rl] / fmaxf(sa[rl], 1e-8f);
            float sig = 1.0f / (1.0f + expf(-u));  // fp32 cliff identical to ref
            Gout[row] = 1.0f - gamp[0] * sig;
        }
    }
}

// ---------------------------------------------------------------------------
// Y = X + gelu(alpha*Macc + bg); alpha = G/(E*max(G*T/E,1e-8))
// ---------------------------------------------------------------------------
__global__ __launch_bounds__(256)
void fuse_y(const float* __restrict__ X, const float* __restrict__ Macc,
            const float* __restrict__ G, const float* __restrict__ E,
            const float* __restrict__ T, const float* __restrict__ bg,
            __hip_bfloat16* __restrict__ Yhi, __hip_bfloat16* __restrict__ Ylo)
{
    const int i   = blockIdx.x * 256 + threadIdx.x;
    const int row = i / DD;
    const int col = i - row * DD;
    const float g = G[row], e = E[row], t = T[row];
    const float denom = fmaxf(g * t / e, 1e-8f);
    const float alpha = g / (e * denom);
    const float m = alpha * Macc[i];
    const float y = X[i] + gelu_f(m + bg[col]);
    __hip_bfloat16 h = f2bf(y);
    Yhi[i] = h;
    Ylo[i] = f2bf(y - bf2f(h));
}

// ---------------------------------------------------------------------------
extern "C" void kernel_launch(void* const* d_in, const int* in_sizes, int n_in,
                              void* d_out, int out_size, void* d_ws, size_t ws_size,
                              hipStream_t stream)
{
    (void)in_sizes; (void)n_in; (void)out_size; (void)ws_size;
    const float* X   = (const float*)d_in[0];
    const float* Wq  = (const float*)d_in[1];
    const float* Wk  = (const float*)d_in[2];
    const float* Wg  = (const float*)d_in[3];
    const float* bg  = (const float*)d_in[4];
    const float* gam = (const float*)d_in[5];
    const float* iW1 = (const float*)d_in[6];
    const float* ib1 = (const float*)d_in[7];
    const float* iW2 = (const float*)d_in[8];
    const float* ib2 = (const float*)d_in[9];
    const float* iWh = (const float*)d_in[10];
    const float* ibh = (const float*)d_in[11];
    const float* fW1 = (const float*)d_in[12];
    const float* fb1 = (const float*)d_in[13];
    const float* fW2 = (const float*)d_in[14];
    const float* fb2 = (const float*)d_in[15];
    const float* fWh = (const float*)d_in[16];
    const float* fbh = (const float*)d_in[17];
    float* out = (float*)d_out;

    char* cur = (char*)d_ws;
    auto alloc = [&](size_t bytes) -> char* {
        char* p = cur;
        cur += (bytes + 255) & ~(size_t)255;
        return p;
    };
    typedef __hip_bfloat16 bf;

    // Region A (67.1 MB): Wp panel, aliased over buffers that are dead during
    // the attention phase (Xhi/Xlo/H1*/H2*).
    char* regA = alloc((size_t)NT * PANEL * 2);
    bf* Wp   = (bf*)regA;
    bf* Xhi  = (bf*)(regA);
    bf* Xlo  = (bf*)(regA + (size_t)NT * DD * 2);
    bf* H1hi = (bf*)(regA + (size_t)NT * DD * 4);
    bf* H1lo = (bf*)(regA + (size_t)NT * DD * 4 + (size_t)NT * DH1 * 2);
    bf* H2hi = (bf*)(regA + (size_t)NT * DD * 4 + (size_t)NT * DH1 * 4);
    bf* H2lo = (bf*)(regA + (size_t)NT * DD * 4 + (size_t)NT * DH1 * 4 + (size_t)NT * DH2 * 2);

    bf* WqkvT  = (bf*)alloc((size_t)3 * DD * DD * 2);    // 2304 x 768
    bf* iW1hiT = (bf*)alloc((size_t)DH1 * DD * 2);
    bf* iW1loT = (bf*)alloc((size_t)DH1 * DD * 2);
    bf* iW2hiT = (bf*)alloc((size_t)DH2 * DH1 * 2);
    bf* iW2loT = (bf*)alloc((size_t)DH2 * DH1 * 2);
    bf* fW1hiT = (bf*)alloc((size_t)DH1 * DD * 2);
    bf* fW1loT = (bf*)alloc((size_t)DH1 * DD * 2);
    bf* fW2hiT = (bf*)alloc((size_t)DH2 * DH1 * 2);
    bf* fW2loT = (bf*)alloc((size_t)DH2 * DH1 * 2);
    bf* QKV    = (bf*)alloc((size_t)NT * 3 * DD * 2);    // 8192 x 2304
    bf* VbT    = (bf*)alloc((size_t)DD * NT * 2);        // 768 x 8192
    float* G    = (float*)alloc((size_t)NT * 4);
    float* E    = (float*)alloc((size_t)NT * 4);
    float* T    = (float*)alloc((size_t)NT * 4);
    float* Macc = (float*)alloc((size_t)NT * DD * 4);
    bf* Yhi    = (bf*)alloc((size_t)NT * DD * 2);
    bf* Ylo    = (bf*)alloc((size_t)NT * DD * 2);

    const dim3 blk(256);

    // 1. converts / transposes
    cvt_split<<<dim3(NT * DD / 1024), blk, 0, stream>>>(X, Xhi, Xlo);
    transpose_f2b<<<dim3(DD / 32, DD / 32), blk, 0, stream>>>(Wq, DD, WqkvT, nullptr, DD);
    transpose_f2b<<<dim3(DD / 32, DD / 32), blk, 0, stream>>>(Wk, DD, WqkvT + (size_t)DD * DD, nullptr, DD);
    transpose_f2b<<<dim3(DD / 32, DD / 32), blk, 0, stream>>>(Wg, DD, WqkvT + (size_t)2 * DD * DD, nullptr, DD);
    transpose_f2b<<<dim3(DH1 / 32, DD / 32), blk, 0, stream>>>(iW1, DH1, iW1hiT, iW1loT, DD);
    transpose_f2b<<<dim3(DH2 / 32, DH1 / 32), blk, 0, stream>>>(iW2, DH2, iW2hiT, iW2loT, DH1);
    transpose_f2b<<<dim3(DH1 / 32, DD / 32), blk, 0, stream>>>(fW1, DH1, fW1hiT, fW1loT, DD);
    transpose_f2b<<<dim3(DH2 / 32, DH1 / 32), blk, 0, stream>>>(fW2, DH2, fW2hiT, fW2loT, DH1);

    // 2. head 1 (split-bf16 for G-cliff safety)
    gemm_bt<1, true, 64, 64><<<dim3(DH1 / 64, NT / 64), blk, 0, stream>>>(
        Xhi, Xlo, DD, iW1hiT, iW1loT, DD, H1hi, H1lo, nullptr, DH1, ib1, nullptr, nullptr, nullptr, DD, 0);
    gemm_bt<1, true, 64, 64><<<dim3(DH2 / 64, NT / 64), blk, 0, stream>>>(
        H1hi, H1lo, DH1, iW2hiT, iW2loT, DH1, H2hi, H2lo, nullptr, DH2, ib2, nullptr, nullptr, nullptr, DH1, 0);
    head_tail<<<dim3(NT / 64), blk, 0, stream>>>(H2hi, H2lo, iWh, ibh, gam, out, G);

    // 3. QKV projection (last reader of Xhi)
    gemm_bt<0, false, 128, 128><<<dim3(3 * DD / 128, NT / 128), blk, 0, stream>>>(
        Xhi, nullptr, DD, WqkvT, nullptr, DD, QKV, nullptr, nullptr, 3 * DD,
        nullptr, nullptr, nullptr, nullptr, DD, 0);
    transpose_b2b<<<dim3(DD / 32, NT / 32), blk, 0, stream>>>(QKV + 2 * DD, 3 * DD, VbT, NT);

    hipMemsetAsync(E, 0, (size_t)NT * 4, stream);
    hipMemsetAsync(T, 0, (size_t)NT * 4, stream);

    // 4. attention panels (4096 cols each); Wp clobbers region A (dead bufs)
    for (int p = 0; p < NPAN; ++p) {
        const bf* Kp = QKV + (size_t)p * PANEL * (3 * DD) + DD;
        gemm_bt<2, false, 128, 128><<<dim3(PANEL / 128, NT / 128), blk, 0, stream>>>(
            QKV, nullptr, 3 * DD, Kp, nullptr, 3 * DD, Wp, nullptr, nullptr, PANEL,
            nullptr, G + p * PANEL, E, T, DD, 0);
        gemm_bt<3, false, 128, 64><<<dim3(DD / 64, NT / 128), blk, 0, stream>>>(
            Wp, nullptr, PANEL, VbT + p * PANEL, nullptr, NT, nullptr, nullptr, Macc, DD,
            nullptr, nullptr, nullptr, nullptr, PANEL, p > 0 ? 1 : 0);
    }

    // 5. Y = X + gelu(alpha*Macc + bg). Wp dead after this point.
    fuse_y<<<dim3(NT * DD / 256), blk, 0, stream>>>(X, Macc, G, E, T, bg, Yhi, Ylo);

    // 6. head 2 (re-uses H1*/H2* slots inside region A — Wp is dead)
    gemm_bt<1, true, 64, 64><<<dim3(DH1 / 64, NT / 64), blk, 0, stream>>>(
        Yhi, Ylo, DD, fW1hiT, fW1loT, DD, H1hi, H1lo, nullptr, DH1, fb1, nullptr, nullptr, nullptr, DD, 0);
    gemm_bt<1, true, 64, 64><<<dim3(DH2 / 64, NT / 64), blk, 0, stream>>>(
        H1hi, H1lo, DH1, fW2hiT, fW2loT, DH1, H2hi, H2lo, nullptr, DH2, fb2, nullptr, nullptr, nullptr, DH1, 0);
    head_tail<<<dim3(NT / 64), blk, 0, stream>>>(H2hi, H2lo, fWh, fbh, gam, out + 4 * NT, nullptr);
}

// Round 5
// 689.141 us; speedup vs baseline: 1.0637x; 1.0637x over previous
//
#include <hip/hip_runtime.h>
#include <hip/hip_bf16.h>
#include <math.h>
#include <stdint.h>
#include <stddef.h>

// ---------------------------------------------------------------------------
// MetaEvidentialGSL: N=8192, D=768, H1=512, H2=256
//  1. split X into bf16 hi/lo; transpose+convert weights to bf16
//  2. head1 via split-bf16 MFMA GEMMs -> m0,v0,a0,b0 + gate G
//  3. QKV = X @ [Wq|Wk|Wg] (one bf16 GEMM); V transposed
//  4. attention in 2 panels of 4096: Wp = exp(QK^T/sqrt(D))*G_j (bf16) with
//     row-sum atomics E/T; Macc = / += Wp @ V (fp32)
//  5. Y = X + gelu(alpha*Macc + bg), alpha = G/(E*max(G*T/E,1e-8))
//  6. head2 on Y -> mu,v,al,be
// R2: XOR swizzle killed bank conflicts (3.5M -> 0).
// R3: BK=64/PANEL=4096 — neutral (latency-bound, all pipes <27%).
// R4: LDS double-buffer + raw vmcnt(N) barrier — EPI=2 improved, but EPI=3
//     exposed as fetch-bound: 297 MB/dispatch (Wp panels re-fetched per XCD).
// R5: XCD-aware block remap — all column-blocks sharing an A row-panel land
//     on ONE XCD (lin%8 round-robin assumption), so each panel is fetched
//     into that XCD's L2 once. Applies to all GEMMs.
// ---------------------------------------------------------------------------

#define NT    8192
#define DD    768
#define DH1   512
#define DH2   256
#define PANEL 4096
#define NPAN  (NT / PANEL)

typedef __attribute__((ext_vector_type(8))) short  short8;
typedef __attribute__((ext_vector_type(4))) float  f32x4;

#define MFMA16(a, b, c) __builtin_amdgcn_mfma_f32_16x16x32_bf16((a), (b), (c), 0, 0, 0)

__device__ __forceinline__ float bf2f(__hip_bfloat16 x) { return __bfloat162float(x); }
__device__ __forceinline__ __hip_bfloat16 f2bf(float x) { return __float2bfloat16(x); }

__device__ __forceinline__ float gelu_f(float x) {
    return 0.5f * x * (1.0f + erff(x * 0.7071067811865476f));
}
__device__ __forceinline__ float softplus_f(float x) {
    return (x > 20.0f) ? x : log1pf(expf(x));
}

// async 16B/lane global->LDS. LDS dest must be wave-uniform base + lane*16.
__device__ __forceinline__ void gload16(const __hip_bfloat16* g, __hip_bfloat16* l) {
    __builtin_amdgcn_global_load_lds(
        (const __attribute__((address_space(1))) void*)(const void*)g,
        (__attribute__((address_space(3))) void*)(void*)l,
        16, 0, 0);
}

// wait until <=N vm ops outstanding, then barrier. N = loads just issued for
// the NEXT buffer; everything older (the buffer we're about to read) is done.
template <int N>
__device__ __forceinline__ void wait_barrier() {
    asm volatile("s_waitcnt vmcnt(%0)\n\ts_barrier" :: "i"(N) : "memory");
}
__device__ __forceinline__ void plain_barrier() {
    asm volatile("s_barrier" ::: "memory");
}

// XCD-aware remap: MI355X round-robins linear workgroup id across 8 XCDs
// (id % 8). Remap so all gridDim.x column-blocks of one A row-panel get ids
// congruent mod 8 -> same XCD -> its L2 fetches that panel once. Bijection
// whenever 8 | gridDim.y (true for every launch here).
__device__ __forceinline__ void xcd_remap(int& bx, int& by) {
    const int nbx = gridDim.x, nby = gridDim.y;
    if ((nby & 7) == 0) {
        const int lin = by * nbx + bx;
        const int x   = lin & 7;
        const int s   = lin >> 3;
        bx = s % nbx;
        by = x + 8 * (s / nbx);
    }
}

// ---------------------------------------------------------------------------
// GEMM: C(MxN) = A(MxK) @ Bt(NxK)^T. Tile TM x TN, BK=32, 4 waves, 256 thr.
// Double-buffered LDS; R2's proven-zero-conflict XOR chunk swizzle:
// 16B chunk c of row r stored at slot c ^ ((r>>1)&3).
// SPLIT: A,B given as hi+lo bf16 pairs; computes hi*hi + hi*lo + lo*hi.
// EPI: 0 = store bf16; 1 = bias+gelu -> split bf16 (hi/lo)
//      2 = w=exp(acc/sqrt(D))*G[col] -> bf16, atomic rowsum E (exp) / T (w)
//      3 = fp32 store (accin=0) or accumulate (accin=1)
// ---------------------------------------------------------------------------
template <int EPI, bool SPLIT, int TM, int TN>
__global__ __launch_bounds__(256)
void gemm_bt(const __hip_bfloat16* __restrict__ Ahi, const __hip_bfloat16* __restrict__ Alo, int lda,
             const __hip_bfloat16* __restrict__ Bhi, const __hip_bfloat16* __restrict__ Blo, int ldb,
             __hip_bfloat16* __restrict__ obf_hi, __hip_bfloat16* __restrict__ obf_lo,
             float* __restrict__ ofp, int ldc,
             const float* __restrict__ bias, const float* __restrict__ Gv,
             float* __restrict__ Esum, float* __restrict__ Tsum, int K, int accin)
{
    constexpr int NB  = SPLIT ? 2 : 1;
    constexpr int WRM = (TM == 128 && TN == 128) ? 2 : (TM == 128 ? 4 : 2);
    constexpr int WCN = 4 / WRM;
    constexpr int WTM = TM / WRM;
    constexpr int WTN = TN / WCN;
    constexpr int MI  = WTM / 16;
    constexpr int NI  = WTN / 16;
    constexpr int PA  = TM / 64;          // staging passes (64 rows x 64 B)
    constexpr int PB  = TN / 64;
    constexpr int LPI = (PA + PB) * NB;   // DMA loads per thread per iter

    __shared__ __align__(16) __hip_bfloat16 As[NB][2][TM * 32];
    __shared__ __align__(16) __hip_bfloat16 Bs[NB][2][TN * 32];

    const int tid  = threadIdx.x;
    const int wave = tid >> 6;
    const int lane = tid & 63;
    int bx = blockIdx.x, by = blockIdx.y;
    xcd_remap(bx, by);
    const int tm = by * TM;
    const int tn = bx * TN;

    // staging: thread stages one 16B chunk: row = tid>>2, chunk = tid&3.
    // LDS slot (tid&3) receives global chunk (tid&3)^((srow>>1)&3).
    const int srow  = tid >> 2;
    const int sgcol = ((tid & 3) ^ ((srow >> 1) & 3)) * 8;
    const int lofs  = srow * 32 + (tid & 3) * 8;

    size_t aoffs[PA], boffs[PB];
#pragma unroll
    for (int p = 0; p < PA; ++p) aoffs[p] = (size_t)(tm + p * 64 + srow) * lda + sgcol;
#pragma unroll
    for (int p = 0; p < PB; ++p) boffs[p] = (size_t)(tn + p * 64 + srow) * ldb + sgcol;

    auto stage = [&](int k0, int buf) {
#pragma unroll
        for (int p = 0; p < PA; ++p)
            gload16(Ahi + aoffs[p] + k0, &As[0][buf][p * 2048 + lofs]);
#pragma unroll
        for (int p = 0; p < PB; ++p)
            gload16(Bhi + boffs[p] + k0, &Bs[0][buf][p * 2048 + lofs]);
        if constexpr (SPLIT) {
#pragma unroll
            for (int p = 0; p < PA; ++p)
                gload16(Alo + aoffs[p] + k0, &As[1][buf][p * 2048 + lofs]);
#pragma unroll
            for (int p = 0; p < PB; ++p)
                gload16(Blo + boffs[p] + k0, &Bs[1][buf][p * 2048 + lofs]);
        }
    };

    f32x4 acc[MI][NI];
#pragma unroll
    for (int i = 0; i < MI; ++i)
#pragma unroll
        for (int j = 0; j < NI; ++j) {
            f32x4 z = {0.0f, 0.0f, 0.0f, 0.0f};
            acc[i][j] = z;
        }

    const int wm   = (wave / WCN) * WTM;
    const int wn   = (wave % WCN) * WTN;
    const int l16  = lane & 15;
    const int quad = lane >> 4;
    const int rchunk = (quad ^ ((l16 >> 1) & 3)) * 8;   // read-side swizzle
    const int arow0  = (wm + l16) * 32 + rchunk;
    const int brow0  = (wn + l16) * 32 + rchunk;

    const int nIter = K >> 5;
    stage(0, 0);
    for (int k = 0; k < nIter; ++k) {
        const int cb = k & 1;
        if (k + 1 < nIter) {
            stage((k + 1) << 5, cb ^ 1);
            wait_barrier<LPI>();   // prev-buffer loads landed; next-buffer in flight
        } else {
            wait_barrier<0>();
        }

        short8 ah[MI], bh[NI];
#pragma unroll
        for (int i = 0; i < MI; ++i) ah[i] = *(const short8*)&As[0][cb][arow0 + i * 512];
#pragma unroll
        for (int j = 0; j < NI; ++j) bh[j] = *(const short8*)&Bs[0][cb][brow0 + j * 512];
        if constexpr (SPLIT) {
            short8 al[MI], bl[NI];
#pragma unroll
            for (int i = 0; i < MI; ++i) al[i] = *(const short8*)&As[1][cb][arow0 + i * 512];
#pragma unroll
            for (int j = 0; j < NI; ++j) bl[j] = *(const short8*)&Bs[1][cb][brow0 + j * 512];
#pragma unroll
            for (int mi = 0; mi < MI; ++mi)
#pragma unroll
                for (int ni = 0; ni < NI; ++ni) {
                    acc[mi][ni] = MFMA16(ah[mi], bh[ni], acc[mi][ni]);
                    acc[mi][ni] = MFMA16(ah[mi], bl[ni], acc[mi][ni]);
                    acc[mi][ni] = MFMA16(al[mi], bh[ni], acc[mi][ni]);
                }
        } else {
#pragma unroll
            for (int mi = 0; mi < MI; ++mi)
#pragma unroll
                for (int ni = 0; ni < NI; ++ni)
                    acc[mi][ni] = MFMA16(ah[mi], bh[ni], acc[mi][ni]);
        }
        plain_barrier();   // all waves done reading buf cb before it's restaged
    }

    // C/D layout: col = lane&15, row = (lane>>4)*4 + reg  [verified m89/m91]
    const int rbase = tm + wm + quad * 4;
    const int cbase = tn + wn + l16;

    if constexpr (EPI == 0) {
#pragma unroll
        for (int mi = 0; mi < MI; ++mi)
#pragma unroll
            for (int ni = 0; ni < NI; ++ni) {
                f32x4 v = acc[mi][ni];
                const int col = cbase + ni * 16;
#pragma unroll
                for (int r = 0; r < 4; ++r)
                    obf_hi[(size_t)(rbase + mi * 16 + r) * ldc + col] = f2bf(v[r]);
            }
    } else if constexpr (EPI == 1) {
#pragma unroll
        for (int mi = 0; mi < MI; ++mi)
#pragma unroll
            for (int ni = 0; ni < NI; ++ni) {
                f32x4 v = acc[mi][ni];
                const int col = cbase + ni * 16;
                const float b = bias[col];
#pragma unroll
                for (int r = 0; r < 4; ++r) {
                    float g = gelu_f(v[r] + b);
                    __hip_bfloat16 h = f2bf(g);
                    size_t idx = (size_t)(rbase + mi * 16 + r) * ldc + col;
                    obf_hi[idx] = h;
                    obf_lo[idx] = f2bf(g - bf2f(h));
                }
            }
    } else if constexpr (EPI == 2) {
        const float SCL = 0.03608439182435161f;   // 1/sqrt(768)
#pragma unroll
        for (int mi = 0; mi < MI; ++mi) {
            float sE[4] = {0.f, 0.f, 0.f, 0.f};
            float sT[4] = {0.f, 0.f, 0.f, 0.f};
#pragma unroll
            for (int ni = 0; ni < NI; ++ni) {
                f32x4 v = acc[mi][ni];
                const int col = cbase + ni * 16;
                const float g = Gv[col];
#pragma unroll
                for (int r = 0; r < 4; ++r) {
                    float we = __expf(v[r] * SCL);
                    float w  = we * g;
                    obf_hi[(size_t)(rbase + mi * 16 + r) * ldc + col] = f2bf(w);
                    sE[r] += we;
                    sT[r] += w;
                }
            }
#pragma unroll
            for (int st = 1; st < 16; st <<= 1)
#pragma unroll
                for (int r = 0; r < 4; ++r) {
                    sE[r] += __shfl_xor(sE[r], st);
                    sT[r] += __shfl_xor(sT[r], st);
                }
            if (l16 == 0) {
#pragma unroll
                for (int r = 0; r < 4; ++r) {
                    atomicAdd(&Esum[rbase + mi * 16 + r], sE[r]);
                    atomicAdd(&Tsum[rbase + mi * 16 + r], sT[r]);
                }
            }
        }
    } else {  // EPI == 3: fp32 store / accumulate
#pragma unroll
        for (int mi = 0; mi < MI; ++mi)
#pragma unroll
            for (int ni = 0; ni < NI; ++ni) {
                f32x4 v = acc[mi][ni];
                const int col = cbase + ni * 16;
#pragma unroll
                for (int r = 0; r < 4; ++r) {
                    size_t idx = (size_t)(rbase + mi * 16 + r) * ldc + col;
                    if (accin) ofp[idx] += v[r];
                    else       ofp[idx]  = v[r];
                }
            }
    }
}

// ---------------------------------------------------------------------------
// transpose f32 (RxC) -> bf16 (CxR), optional lo residual output
// ---------------------------------------------------------------------------
__global__ __launch_bounds__(256)
void transpose_f2b(const float* __restrict__ in, int ldin,
                   __hip_bfloat16* __restrict__ ohi, __hip_bfloat16* __restrict__ olo, int ldout)
{
    __shared__ float t[32][33];
    const int tx = threadIdx.x & 31;
    const int ty = threadIdx.x >> 5;
    const int r0 = blockIdx.y * 32;
    const int c0 = blockIdx.x * 32;
#pragma unroll
    for (int j = 0; j < 32; j += 8)
        t[ty + j][tx] = in[(size_t)(r0 + ty + j) * ldin + c0 + tx];
    __syncthreads();
#pragma unroll
    for (int j = 0; j < 32; j += 8) {
        float x = t[tx][ty + j];
        __hip_bfloat16 h = f2bf(x);
        size_t o = (size_t)(c0 + ty + j) * ldout + r0 + tx;
        ohi[o] = h;
        if (olo) olo[o] = f2bf(x - bf2f(h));
    }
}

__global__ __launch_bounds__(256)
void transpose_b2b(const __hip_bfloat16* __restrict__ in, int ldin,
                   __hip_bfloat16* __restrict__ out, int ldout)
{
    __shared__ __hip_bfloat16 t[32][33];
    const int tx = threadIdx.x & 31;
    const int ty = threadIdx.x >> 5;
    const int r0 = blockIdx.y * 32;
    const int c0 = blockIdx.x * 32;
#pragma unroll
    for (int j = 0; j < 32; j += 8)
        t[ty + j][tx] = in[(size_t)(r0 + ty + j) * ldin + c0 + tx];
    __syncthreads();
#pragma unroll
    for (int j = 0; j < 32; j += 8)
        out[(size_t)(c0 + ty + j) * ldout + r0 + tx] = t[tx][ty + j];
}

__global__ __launch_bounds__(256)
void cvt_split(const float* __restrict__ in, __hip_bfloat16* __restrict__ hi,
               __hip_bfloat16* __restrict__ lo)
{
    const int i = (blockIdx.x * 256 + threadIdx.x) * 4;
    f32x4 v = *(const f32x4*)(in + i);
#pragma unroll
    for (int k = 0; k < 4; ++k) {
        __hip_bfloat16 h = f2bf(v[k]);
        hi[i + k] = h;
        lo[i + k] = f2bf(v[k] - bf2f(h));
    }
}

// ---------------------------------------------------------------------------
// head tail: r = H2 @ Wh + bh (fp32, hi+lo input), NIG transforms, optional G.
// ---------------------------------------------------------------------------
__global__ __launch_bounds__(256)
void head_tail(const __hip_bfloat16* __restrict__ H2hi, const __hip_bfloat16* __restrict__ H2lo,
               const float* __restrict__ Wh, const float* __restrict__ bh,
               const float* __restrict__ gamp,
               float* __restrict__ outBase, float* __restrict__ Gout)
{
    __shared__ float sa[64], sb[64];
    const int tid = threadIdx.x;
    const int rl  = tid >> 2;
    const int c   = tid & 3;
    const int row = blockIdx.x * 64 + rl;
    const __hip_bfloat16* hh = H2hi + (size_t)row * DH2;
    const __hip_bfloat16* hl = H2lo + (size_t)row * DH2;
    float acc = bh[c];
    for (int k = 0; k < DH2; ++k) {
        float h = bf2f(hh[k]) + bf2f(hl[k]);
        acc = fmaf(h, Wh[k * 4 + c], acc);
    }
    float sp = softplus_f(acc);
    if (c == 0) {
        outBase[row] = acc;                        // mu
    } else if (c == 1) {
        outBase[NT + row] = sp + 1e-6f;            // v
    } else if (c == 2) {
        float a0 = (sp + 1.0f) + 1e-6f;            // match ref assoc order
        outBase[2 * NT + row] = a0;
        if (Gout) sa[rl] = a0 - 1.0f;              // match ref's a0-1 rounding
    } else {
        float b0 = sp + 1e-6f;
        outBase[3 * NT + row] = b0;
        if (Gout) sb[rl] = b0;
    }
    if (Gout != nullptr) {
        __syncthreads();
        if (c == 0) {
            float u   = sb[rl] / fmaxf(sa[rl], 1e-8f);
            float sig = 1.0f / (1.0f + expf(-u));  // fp32 cliff identical to ref
            Gout[row] = 1.0f - gamp[0] * sig;
        }
    }
}

// ---------------------------------------------------------------------------
// Y = X + gelu(alpha*Macc + bg); alpha = G/(E*max(G*T/E,1e-8))
// ---------------------------------------------------------------------------
__global__ __launch_bounds__(256)
void fuse_y(const float* __restrict__ X, const float* __restrict__ Macc,
            const float* __restrict__ G, const float* __restrict__ E,
            const float* __restrict__ T, const float* __restrict__ bg,
            __hip_bfloat16* __restrict__ Yhi, __hip_bfloat16* __restrict__ Ylo)
{
    const int i   = blockIdx.x * 256 + threadIdx.x;
    const int row = i / DD;
    const int col = i - row * DD;
    const float g = G[row], e = E[row], t = T[row];
    const float denom = fmaxf(g * t / e, 1e-8f);
    const float alpha = g / (e * denom);
    const float m = alpha * Macc[i];
    const float y = X[i] + gelu_f(m + bg[col]);
    __hip_bfloat16 h = f2bf(y);
    Yhi[i] = h;
    Ylo[i] = f2bf(y - bf2f(h));
}

// ---------------------------------------------------------------------------
extern "C" void kernel_launch(void* const* d_in, const int* in_sizes, int n_in,
                              void* d_out, int out_size, void* d_ws, size_t ws_size,
                              hipStream_t stream)
{
    (void)in_sizes; (void)n_in; (void)out_size; (void)ws_size;
    const float* X   = (const float*)d_in[0];
    const float* Wq  = (const float*)d_in[1];
    const float* Wk  = (const float*)d_in[2];
    const float* Wg  = (const float*)d_in[3];
    const float* bg  = (const float*)d_in[4];
    const float* gam = (const float*)d_in[5];
    const float* iW1 = (const float*)d_in[6];
    const float* ib1 = (const float*)d_in[7];
    const float* iW2 = (const float*)d_in[8];
    const float* ib2 = (const float*)d_in[9];
    const float* iWh = (const float*)d_in[10];
    const float* ibh = (const float*)d_in[11];
    const float* fW1 = (const float*)d_in[12];
    const float* fb1 = (const float*)d_in[13];
    const float* fW2 = (const float*)d_in[14];
    const float* fb2 = (const float*)d_in[15];
    const float* fWh = (const float*)d_in[16];
    const float* fbh = (const float*)d_in[17];
    float* out = (float*)d_out;

    char* cur = (char*)d_ws;
    auto alloc = [&](size_t bytes) -> char* {
        char* p = cur;
        cur += (bytes + 255) & ~(size_t)255;
        return p;
    };
    typedef __hip_bfloat16 bf;

    // Region A (67.1 MB): Wp panel, aliased over buffers that are dead during
    // the attention phase (Xhi/Xlo/H1*/H2*).
    char* regA = alloc((size_t)NT * PANEL * 2);
    bf* Wp   = (bf*)regA;
    bf* Xhi  = (bf*)(regA);
    bf* Xlo  = (bf*)(regA + (size_t)NT * DD * 2);
    bf* H1hi = (bf*)(regA + (size_t)NT * DD * 4);
    bf* H1lo = (bf*)(regA + (size_t)NT * DD * 4 + (size_t)NT * DH1 * 2);
    bf* H2hi = (bf*)(regA + (size_t)NT * DD * 4 + (size_t)NT * DH1 * 4);
    bf* H2lo = (bf*)(regA + (size_t)NT * DD * 4 + (size_t)NT * DH1 * 4 + (size_t)NT * DH2 * 2);

    bf* WqkvT  = (bf*)alloc((size_t)3 * DD * DD * 2);    // 2304 x 768
    bf* iW1hiT = (bf*)alloc((size_t)DH1 * DD * 2);
    bf* iW1loT = (bf*)alloc((size_t)DH1 * DD * 2);
    bf* iW2hiT = (bf*)alloc((size_t)DH2 * DH1 * 2);
    bf* iW2loT = (bf*)alloc((size_t)DH2 * DH1 * 2);
    bf* fW1hiT = (bf*)alloc((size_t)DH1 * DD * 2);
    bf* fW1loT = (bf*)alloc((size_t)DH1 * DD * 2);
    bf* fW2hiT = (bf*)alloc((size_t)DH2 * DH1 * 2);
    bf* fW2loT = (bf*)alloc((size_t)DH2 * DH1 * 2);
    bf* QKV    = (bf*)alloc((size_t)NT * 3 * DD * 2);    // 8192 x 2304
    bf* VbT    = (bf*)alloc((size_t)DD * NT * 2);        // 768 x 8192
    float* G    = (float*)alloc((size_t)NT * 4);
    float* E    = (float*)alloc((size_t)NT * 4);
    float* T    = (float*)alloc((size_t)NT * 4);
    float* Macc = (float*)alloc((size_t)NT * DD * 4);
    bf* Yhi    = (bf*)alloc((size_t)NT * DD * 2);
    bf* Ylo    = (bf*)alloc((size_t)NT * DD * 2);

    const dim3 blk(256);

    // 1. converts / transposes
    cvt_split<<<dim3(NT * DD / 1024), blk, 0, stream>>>(X, Xhi, Xlo);
    transpose_f2b<<<dim3(DD / 32, DD / 32), blk, 0, stream>>>(Wq, DD, WqkvT, nullptr, DD);
    transpose_f2b<<<dim3(DD / 32, DD / 32), blk, 0, stream>>>(Wk, DD, WqkvT + (size_t)DD * DD, nullptr, DD);
    transpose_f2b<<<dim3(DD / 32, DD / 32), blk, 0, stream>>>(Wg, DD, WqkvT + (size_t)2 * DD * DD, nullptr, DD);
    transpose_f2b<<<dim3(DH1 / 32, DD / 32), blk, 0, stream>>>(iW1, DH1, iW1hiT, iW1loT, DD);
    transpose_f2b<<<dim3(DH2 / 32, DH1 / 32), blk, 0, stream>>>(iW2, DH2, iW2hiT, iW2loT, DH1);
    transpose_f2b<<<dim3(DH1 / 32, DD / 32), blk, 0, stream>>>(fW1, DH1, fW1hiT, fW1loT, DD);
    transpose_f2b<<<dim3(DH2 / 32, DH1 / 32), blk, 0, stream>>>(fW2, DH2, fW2hiT, fW2loT, DH1);

    // 2. head 1 (split-bf16 for G-cliff safety)
    gemm_bt<1, true, 64, 64><<<dim3(DH1 / 64, NT / 64), blk, 0, stream>>>(
        Xhi, Xlo, DD, iW1hiT, iW1loT, DD, H1hi, H1lo, nullptr, DH1, ib1, nullptr, nullptr, nullptr, DD, 0);
    gemm_bt<1, true, 64, 64><<<dim3(DH2 / 64, NT / 64), blk, 0, stream>>>(
        H1hi, H1lo, DH1, iW2hiT, iW2loT, DH1, H2hi, H2lo, nullptr, DH2, ib2, nullptr, nullptr, nullptr, DH1, 0);
    head_tail<<<dim3(NT / 64), blk, 0, stream>>>(H2hi, H2lo, iWh, ibh, gam, out, G);

    // 3. QKV projection (last reader of Xhi)
    gemm_bt<0, false, 128, 128><<<dim3(3 * DD / 128, NT / 128), blk, 0, stream>>>(
        Xhi, nullptr, DD, WqkvT, nullptr, DD, QKV, nullptr, nullptr, 3 * DD,
        nullptr, nullptr, nullptr, nullptr, DD, 0);
    transpose_b2b<<<dim3(DD / 32, NT / 32), blk, 0, stream>>>(QKV + 2 * DD, 3 * DD, VbT, NT);

    hipMemsetAsync(E, 0, (size_t)NT * 4, stream);
    hipMemsetAsync(T, 0, (size_t)NT * 4, stream);

    // 4. attention panels (4096 cols each); Wp clobbers region A (dead bufs)
    for (int p = 0; p < NPAN; ++p) {
        const bf* Kp = QKV + (size_t)p * PANEL * (3 * DD) + DD;
        gemm_bt<2, false, 128, 128><<<dim3(PANEL / 128, NT / 128), blk, 0, stream>>>(
            QKV, nullptr, 3 * DD, Kp, nullptr, 3 * DD, Wp, nullptr, nullptr, PANEL,
            nullptr, G + p * PANEL, E, T, DD, 0);
        gemm_bt<3, false, 128, 64><<<dim3(DD / 64, NT / 128), blk, 0, stream>>>(
            Wp, nullptr, PANEL, VbT + p * PANEL, nullptr, NT, nullptr, nullptr, Macc, DD,
            nullptr, nullptr, nullptr, nullptr, PANEL, p > 0 ? 1 : 0);
    }

    // 5. Y = X + gelu(alpha*Macc + bg). Wp dead after this point.
    fuse_y<<<dim3(NT * DD / 256), blk, 0, stream>>>(X, Macc, G, E, T, bg, Yhi, Ylo);

    // 6. head 2 (re-uses H1*/H2* slots inside region A — Wp is dead)
    gemm_bt<1, true, 64, 64><<<dim3(DH1 / 64, NT / 64), blk, 0, stream>>>(
        Yhi, Ylo, DD, fW1hiT, fW1loT, DD, H1hi, H1lo, nullptr, DH1, fb1, nullptr, nullptr, nullptr, DD, 0);
    gemm_bt<1, true, 64, 64><<<dim3(DH2 / 64, NT / 64), blk, 0, stream>>>(
        H1hi, H1lo, DH1, fW2hiT, fW2loT, DH1, H2hi, H2lo, nullptr, DH2, fb2, nullptr, nullptr, nullptr, DH1, 0);
    head_tail<<<dim3(NT / 64), blk, 0, stream>>>(H2hi, H2lo, fWh, fbh, gam, out + 4 * NT, nullptr);
}

// Round 6
// 674.877 us; speedup vs baseline: 1.0862x; 1.0211x over previous
//
#include <hip/hip_runtime.h>
#include <hip/hip_bf16.h>
#include <math.h>
#include <stdint.h>
#include <stddef.h>

// ---------------------------------------------------------------------------
// MetaEvidentialGSL: N=8192, D=768, H1=512, H2=256
// R2: XOR swizzle -> 0 bank conflicts. R4: dbuf + raw vmcnt barrier.
// R5: XCD-aware remap (PV fetch 297->~80 MB). R6: head2 plain bf16 (only
// head1 needs split -- G-cliff), triple-buffer prefetch depth 2.
// ---------------------------------------------------------------------------

#define NT    8192
#define DD    768
#define DH1   512
#define DH2   256
#define PANEL 4096
#define NPAN  (NT / PANEL)

typedef __attribute__((ext_vector_type(8))) short  short8;
typedef __attribute__((ext_vector_type(4))) float  f32x4;

#define MFMA16(a, b, c) __builtin_amdgcn_mfma_f32_16x16x32_bf16((a), (b), (c), 0, 0, 0)

__device__ __forceinline__ float bf2f(__hip_bfloat16 x) { return __bfloat162float(x); }
__device__ __forceinline__ __hip_bfloat16 f2bf(float x) { return __float2bfloat16(x); }

__device__ __forceinline__ float gelu_f(float x) {
    return 0.5f * x * (1.0f + erff(x * 0.7071067811865476f));
}
__device__ __forceinline__ float softplus_f(float x) {
    return (x > 20.0f) ? x : log1pf(expf(x));
}

// async 16B/lane global->LDS. LDS dest must be wave-uniform base + lane*16.
__device__ __forceinline__ void gload16(const __hip_bfloat16* g, __hip_bfloat16* l) {
    __builtin_amdgcn_global_load_lds(
        (const __attribute__((address_space(1))) void*)(const void*)g,
        (__attribute__((address_space(3))) void*)(void*)l,
        16, 0, 0);
}

// wait until <=N vm ops outstanding, then barrier.
template <int N>
__device__ __forceinline__ void wait_barrier() {
    asm volatile("s_waitcnt vmcnt(%0)\n\ts_barrier" :: "i"(N) : "memory");
}
__device__ __forceinline__ void plain_barrier() {
    asm volatile("s_barrier" ::: "memory");
}

// XCD-aware remap: linear workgroup id round-robins across 8 XCDs (id % 8).
// Remap so all column-blocks of one A row-panel share an XCD.
__device__ __forceinline__ void xcd_remap(int& bx, int& by) {
    const int nbx = gridDim.x, nby = gridDim.y;
    if ((nby & 7) == 0) {
        const int lin = by * nbx + bx;
        const int x   = lin & 7;
        const int s   = lin >> 3;
        bx = s % nbx;
        by = x + 8 * (s / nbx);
    }
}

// ---------------------------------------------------------------------------
// GEMM: C(MxN) = A(MxK) @ Bt(NxK)^T. Tile TM x TN, BK=32, 4 waves, 256 thr.
// Triple-buffered LDS, prefetch depth 2 (wait vmcnt(2*LPI)).
// XOR chunk swizzle: 16B chunk c of row r at slot c ^ ((r>>1)&3).
// SPLIT: A,B hi+lo pairs -> hi*hi + hi*lo + lo*hi.
// EPI: 0 = store bf16; 1 = bias+gelu -> bf16 (+lo if obf_lo)
//      2 = w=exp(acc/sqrt(D))*G[col] -> bf16, atomic rowsum E / T
//      3 = fp32 store (accin=0) or accumulate (accin=1)
// ---------------------------------------------------------------------------
template <int EPI, bool SPLIT, int TM, int TN>
__global__ __launch_bounds__(256)
void gemm_bt(const __hip_bfloat16* __restrict__ Ahi, const __hip_bfloat16* __restrict__ Alo, int lda,
             const __hip_bfloat16* __restrict__ Bhi, const __hip_bfloat16* __restrict__ Blo, int ldb,
             __hip_bfloat16* __restrict__ obf_hi, __hip_bfloat16* __restrict__ obf_lo,
             float* __restrict__ ofp, int ldc,
             const float* __restrict__ bias, const float* __restrict__ Gv,
             float* __restrict__ Esum, float* __restrict__ Tsum, int K, int accin)
{
    constexpr int NB  = SPLIT ? 2 : 1;
    constexpr int WRM = (TM == 128 && TN == 128) ? 2 : (TM == 128 ? 4 : 2);
    constexpr int WCN = 4 / WRM;
    constexpr int WTM = TM / WRM;
    constexpr int WTN = TN / WCN;
    constexpr int MI  = WTM / 16;
    constexpr int NI  = WTN / 16;
    constexpr int PA  = TM / 64;          // staging passes (64 rows x 64 B)
    constexpr int PB  = TN / 64;
    constexpr int LPI = (PA + PB) * NB;   // DMA loads per thread per iter

    __shared__ __align__(16) __hip_bfloat16 As[NB][3][TM * 32];
    __shared__ __align__(16) __hip_bfloat16 Bs[NB][3][TN * 32];

    const int tid  = threadIdx.x;
    const int wave = tid >> 6;
    const int lane = tid & 63;
    int bx = blockIdx.x, by = blockIdx.y;
    xcd_remap(bx, by);
    const int tm = by * TM;
    const int tn = bx * TN;

    const int srow  = tid >> 2;
    const int sgcol = ((tid & 3) ^ ((srow >> 1) & 3)) * 8;
    const int lofs  = srow * 32 + (tid & 3) * 8;

    size_t aoffs[PA], boffs[PB];
#pragma unroll
    for (int p = 0; p < PA; ++p) aoffs[p] = (size_t)(tm + p * 64 + srow) * lda + sgcol;
#pragma unroll
    for (int p = 0; p < PB; ++p) boffs[p] = (size_t)(tn + p * 64 + srow) * ldb + sgcol;

    auto stage = [&](int k0, int buf) {
#pragma unroll
        for (int p = 0; p < PA; ++p)
            gload16(Ahi + aoffs[p] + k0, &As[0][buf][p * 2048 + lofs]);
#pragma unroll
        for (int p = 0; p < PB; ++p)
            gload16(Bhi + boffs[p] + k0, &Bs[0][buf][p * 2048 + lofs]);
        if constexpr (SPLIT) {
#pragma unroll
            for (int p = 0; p < PA; ++p)
                gload16(Alo + aoffs[p] + k0, &As[1][buf][p * 2048 + lofs]);
#pragma unroll
            for (int p = 0; p < PB; ++p)
                gload16(Blo + boffs[p] + k0, &Bs[1][buf][p * 2048 + lofs]);
        }
    };

    f32x4 acc[MI][NI];
#pragma unroll
    for (int i = 0; i < MI; ++i)
#pragma unroll
        for (int j = 0; j < NI; ++j) {
            f32x4 z = {0.0f, 0.0f, 0.0f, 0.0f};
            acc[i][j] = z;
        }

    const int wm   = (wave / WCN) * WTM;
    const int wn   = (wave % WCN) * WTN;
    const int l16  = lane & 15;
    const int quad = lane >> 4;
    const int rchunk = (quad ^ ((l16 >> 1) & 3)) * 8;
    const int arow0  = (wm + l16) * 32 + rchunk;
    const int brow0  = (wn + l16) * 32 + rchunk;

    const int nIter = K >> 5;
    stage(0, 0);
    if (nIter > 1) stage(32, 1);
    for (int k = 0; k < nIter; ++k) {
        const int cb = k % 3;
        if (k + 2 < nIter) {
            stage((k + 2) << 5, (k + 2) % 3);
            wait_barrier<2 * LPI>();  // 2 newer stages in flight; buf cb landed
        } else if (k + 1 < nIter) {
            wait_barrier<LPI>();      // 1 newer stage in flight
        } else {
            wait_barrier<0>();
        }

        short8 ah[MI], bh[NI];
#pragma unroll
        for (int i = 0; i < MI; ++i) ah[i] = *(const short8*)&As[0][cb][arow0 + i * 512];
#pragma unroll
        for (int j = 0; j < NI; ++j) bh[j] = *(const short8*)&Bs[0][cb][brow0 + j * 512];
        if constexpr (SPLIT) {
            short8 al[MI], bl[NI];
#pragma unroll
            for (int i = 0; i < MI; ++i) al[i] = *(const short8*)&As[1][cb][arow0 + i * 512];
#pragma unroll
            for (int j = 0; j < NI; ++j) bl[j] = *(const short8*)&Bs[1][cb][brow0 + j * 512];
#pragma unroll
            for (int mi = 0; mi < MI; ++mi)
#pragma unroll
                for (int ni = 0; ni < NI; ++ni) {
                    acc[mi][ni] = MFMA16(ah[mi], bh[ni], acc[mi][ni]);
                    acc[mi][ni] = MFMA16(ah[mi], bl[ni], acc[mi][ni]);
                    acc[mi][ni] = MFMA16(al[mi], bh[ni], acc[mi][ni]);
                }
        } else {
#pragma unroll
            for (int mi = 0; mi < MI; ++mi)
#pragma unroll
                for (int ni = 0; ni < NI; ++ni)
                    acc[mi][ni] = MFMA16(ah[mi], bh[ni], acc[mi][ni]);
        }
        plain_barrier();   // buf cb free; restaged earliest in iter k+1
    }

    // C/D layout: col = lane&15, row = (lane>>4)*4 + reg  [verified m89/m91]
    const int rbase = tm + wm + quad * 4;
    const int cbase = tn + wn + l16;

    if constexpr (EPI == 0) {
#pragma unroll
        for (int mi = 0; mi < MI; ++mi)
#pragma unroll
            for (int ni = 0; ni < NI; ++ni) {
                f32x4 v = acc[mi][ni];
                const int col = cbase + ni * 16;
#pragma unroll
                for (int r = 0; r < 4; ++r)
                    obf_hi[(size_t)(rbase + mi * 16 + r) * ldc + col] = f2bf(v[r]);
            }
    } else if constexpr (EPI == 1) {
#pragma unroll
        for (int mi = 0; mi < MI; ++mi)
#pragma unroll
            for (int ni = 0; ni < NI; ++ni) {
                f32x4 v = acc[mi][ni];
                const int col = cbase + ni * 16;
                const float b = bias[col];
#pragma unroll
                for (int r = 0; r < 4; ++r) {
                    float g = gelu_f(v[r] + b);
                    __hip_bfloat16 h = f2bf(g);
                    size_t idx = (size_t)(rbase + mi * 16 + r) * ldc + col;
                    obf_hi[idx] = h;
                    if (obf_lo) obf_lo[idx] = f2bf(g - bf2f(h));
                }
            }
    } else if constexpr (EPI == 2) {
        const float SCL = 0.03608439182435161f;   // 1/sqrt(768)
#pragma unroll
        for (int mi = 0; mi < MI; ++mi) {
            float sE[4] = {0.f, 0.f, 0.f, 0.f};
            float sT[4] = {0.f, 0.f, 0.f, 0.f};
#pragma unroll
            for (int ni = 0; ni < NI; ++ni) {
                f32x4 v = acc[mi][ni];
                const int col = cbase + ni * 16;
                const float g = Gv[col];
#pragma unroll
                for (int r = 0; r < 4; ++r) {
                    float we = __expf(v[r] * SCL);
                    float w  = we * g;
                    obf_hi[(size_t)(rbase + mi * 16 + r) * ldc + col] = f2bf(w);
                    sE[r] += we;
                    sT[r] += w;
                }
            }
#pragma unroll
            for (int st = 1; st < 16; st <<= 1)
#pragma unroll
                for (int r = 0; r < 4; ++r) {
                    sE[r] += __shfl_xor(sE[r], st);
                    sT[r] += __shfl_xor(sT[r], st);
                }
            if (l16 == 0) {
#pragma unroll
                for (int r = 0; r < 4; ++r) {
                    atomicAdd(&Esum[rbase + mi * 16 + r], sE[r]);
                    atomicAdd(&Tsum[rbase + mi * 16 + r], sT[r]);
                }
            }
        }
    } else {  // EPI == 3: fp32 store / accumulate
#pragma unroll
        for (int mi = 0; mi < MI; ++mi)
#pragma unroll
            for (int ni = 0; ni < NI; ++ni) {
                f32x4 v = acc[mi][ni];
                const int col = cbase + ni * 16;
#pragma unroll
                for (int r = 0; r < 4; ++r) {
                    size_t idx = (size_t)(rbase + mi * 16 + r) * ldc + col;
                    if (accin) ofp[idx] += v[r];
                    else       ofp[idx]  = v[r];
                }
            }
    }
}

// ---------------------------------------------------------------------------
__global__ __launch_bounds__(256)
void transpose_f2b(const float* __restrict__ in, int ldin,
                   __hip_bfloat16* __restrict__ ohi, __hip_bfloat16* __restrict__ olo, int ldout)
{
    __shared__ float t[32][33];
    const int tx = threadIdx.x & 31;
    const int ty = threadIdx.x >> 5;
    const int r0 = blockIdx.y * 32;
    const int c0 = blockIdx.x * 32;
#pragma unroll
    for (int j = 0; j < 32; j += 8)
        t[ty + j][tx] = in[(size_t)(r0 + ty + j) * ldin + c0 + tx];
    __syncthreads();
#pragma unroll
    for (int j = 0; j < 32; j += 8) {
        float x = t[tx][ty + j];
        __hip_bfloat16 h = f2bf(x);
        size_t o = (size_t)(c0 + ty + j) * ldout + r0 + tx;
        ohi[o] = h;
        if (olo) olo[o] = f2bf(x - bf2f(h));
    }
}

__global__ __launch_bounds__(256)
void transpose_b2b(const __hip_bfloat16* __restrict__ in, int ldin,
                   __hip_bfloat16* __restrict__ out, int ldout)
{
    __shared__ __hip_bfloat16 t[32][33];
    const int tx = threadIdx.x & 31;
    const int ty = threadIdx.x >> 5;
    const int r0 = blockIdx.y * 32;
    const int c0 = blockIdx.x * 32;
#pragma unroll
    for (int j = 0; j < 32; j += 8)
        t[ty + j][tx] = in[(size_t)(r0 + ty + j) * ldin + c0 + tx];
    __syncthreads();
#pragma unroll
    for (int j = 0; j < 32; j += 8)
        out[(size_t)(c0 + ty + j) * ldout + r0 + tx] = t[tx][ty + j];
}

__global__ __launch_bounds__(256)
void cvt_split(const float* __restrict__ in, __hip_bfloat16* __restrict__ hi,
               __hip_bfloat16* __restrict__ lo)
{
    const int i = (blockIdx.x * 256 + threadIdx.x) * 4;
    f32x4 v = *(const f32x4*)(in + i);
#pragma unroll
    for (int k = 0; k < 4; ++k) {
        __hip_bfloat16 h = f2bf(v[k]);
        hi[i + k] = h;
        lo[i + k] = f2bf(v[k] - bf2f(h));
    }
}

// ---------------------------------------------------------------------------
// head tail: r = H2 @ Wh + bh (fp32; hi + optional lo), NIG transforms, opt G.
// ---------------------------------------------------------------------------
__global__ __launch_bounds__(256)
void head_tail(const __hip_bfloat16* __restrict__ H2hi, const __hip_bfloat16* __restrict__ H2lo,
               const float* __restrict__ Wh, const float* __restrict__ bh,
               const float* __restrict__ gamp,
               float* __restrict__ outBase, float* __restrict__ Gout)
{
    __shared__ float sa[64], sb[64];
    const int tid = threadIdx.x;
    const int rl  = tid >> 2;
    const int c   = tid & 3;
    const int row = blockIdx.x * 64 + rl;
    const __hip_bfloat16* hh = H2hi + (size_t)row * DH2;
    const __hip_bfloat16* hl = H2lo ? H2lo + (size_t)row * DH2 : nullptr;
    float acc = bh[c];
    if (hl) {
        for (int k = 0; k < DH2; ++k)
            acc = fmaf(bf2f(hh[k]) + bf2f(hl[k]), Wh[k * 4 + c], acc);
    } else {
        for (int k = 0; k < DH2; ++k)
            acc = fmaf(bf2f(hh[k]), Wh[k * 4 + c], acc);
    }
    float sp = softplus_f(acc);
    if (c == 0) {
        outBase[row] = acc;                        // mu
    } else if (c == 1) {
        outBase[NT + row] = sp + 1e-6f;            // v
    } else if (c == 2) {
        float a0 = (sp + 1.0f) + 1e-6f;            // match ref assoc order
        outBase[2 * NT + row] = a0;
        if (Gout) sa[rl] = a0 - 1.0f;
    } else {
        float b0 = sp + 1e-6f;
        outBase[3 * NT + row] = b0;
        if (Gout) sb[rl] = b0;
    }
    if (Gout != nullptr) {
        __syncthreads();
        if (c == 0) {
            float u   = sb[rl] / fmaxf(sa[rl], 1e-8f);
            float sig = 1.0f / (1.0f + expf(-u));
            Gout[row] = 1.0f - gamp[0] * sig;
        }
    }
}

// ---------------------------------------------------------------------------
// Y = X + gelu(alpha*Macc + bg); alpha = G/(E*max(G*T/E,1e-8))
// ---------------------------------------------------------------------------
__global__ __launch_bounds__(256)
void fuse_y(const float* __restrict__ X, const float* __restrict__ Macc,
            const float* __restrict__ G, const float* __restrict__ E,
            const float* __restrict__ T, const float* __restrict__ bg,
            __hip_bfloat16* __restrict__ Yhi)
{
    const int i   = blockIdx.x * 256 + threadIdx.x;
    const int row = i / DD;
    const int col = i - row * DD;
    const float g = G[row], e = E[row], t = T[row];
    const float denom = fmaxf(g * t / e, 1e-8f);
    const float alpha = g / (e * denom);
    const float m = alpha * Macc[i];
    Yhi[i] = f2bf(X[i] + gelu_f(m + bg[col]));
}

// ---------------------------------------------------------------------------
extern "C" void kernel_launch(void* const* d_in, const int* in_sizes, int n_in,
                              void* d_out, int out_size, void* d_ws, size_t ws_size,
                              hipStream_t stream)
{
    (void)in_sizes; (void)n_in; (void)out_size; (void)ws_size;
    const float* X   = (const float*)d_in[0];
    const float* Wq  = (const float*)d_in[1];
    const float* Wk  = (const float*)d_in[2];
    const float* Wg  = (const float*)d_in[3];
    const float* bg  = (const float*)d_in[4];
    const float* gam = (const float*)d_in[5];
    const float* iW1 = (const float*)d_in[6];
    const float* ib1 = (const float*)d_in[7];
    const float* iW2 = (const float*)d_in[8];
    const float* ib2 = (const float*)d_in[9];
    const float* iWh = (const float*)d_in[10];
    const float* ibh = (const float*)d_in[11];
    const float* fW1 = (const float*)d_in[12];
    const float* fb1 = (const float*)d_in[13];
    const float* fW2 = (const float*)d_in[14];
    const float* fb2 = (const float*)d_in[15];
    const float* fWh = (const float*)d_in[16];
    const float* fbh = (const float*)d_in[17];
    float* out = (float*)d_out;

    char* cur = (char*)d_ws;
    auto alloc = [&](size_t bytes) -> char* {
        char* p = cur;
        cur += (bytes + 255) & ~(size_t)255;
        return p;
    };
    typedef __hip_bfloat16 bf;

    // Region A (67.1 MB): Wp panel aliased over attention-phase-dead buffers.
    char* regA = alloc((size_t)NT * PANEL * 2);
    bf* Wp   = (bf*)regA;
    bf* Xhi  = (bf*)(regA);
    bf* Xlo  = (bf*)(regA + (size_t)NT * DD * 2);
    bf* H1hi = (bf*)(regA + (size_t)NT * DD * 4);
    bf* H1lo = (bf*)(regA + (size_t)NT * DD * 4 + (size_t)NT * DH1 * 2);
    bf* H2hi = (bf*)(regA + (size_t)NT * DD * 4 + (size_t)NT * DH1 * 4);
    bf* H2lo = (bf*)(regA + (size_t)NT * DD * 4 + (size_t)NT * DH1 * 4 + (size_t)NT * DH2 * 2);

    bf* WqkvT  = (bf*)alloc((size_t)3 * DD * DD * 2);
    bf* iW1hiT = (bf*)alloc((size_t)DH1 * DD * 2);
    bf* iW1loT = (bf*)alloc((size_t)DH1 * DD * 2);
    bf* iW2hiT = (bf*)alloc((size_t)DH2 * DH1 * 2);
    bf* iW2loT = (bf*)alloc((size_t)DH2 * DH1 * 2);
    bf* fW1hiT = (bf*)alloc((size_t)DH1 * DD * 2);
    bf* fW2hiT = (bf*)alloc((size_t)DH2 * DH1 * 2);
    bf* QKV    = (bf*)alloc((size_t)NT * 3 * DD * 2);
    bf* VbT    = (bf*)alloc((size_t)DD * NT * 2);
    float* G    = (float*)alloc((size_t)NT * 4);
    float* E    = (float*)alloc((size_t)NT * 4);
    float* T    = (float*)alloc((size_t)NT * 4);
    float* Macc = (float*)alloc((size_t)NT * DD * 4);
    bf* Yhi    = (bf*)alloc((size_t)NT * DD * 2);

    const dim3 blk(256);

    // 1. converts / transposes
    cvt_split<<<dim3(NT * DD / 1024), blk, 0, stream>>>(X, Xhi, Xlo);
    transpose_f2b<<<dim3(DD / 32, DD / 32), blk, 0, stream>>>(Wq, DD, WqkvT, nullptr, DD);
    transpose_f2b<<<dim3(DD / 32, DD / 32), blk, 0, stream>>>(Wk, DD, WqkvT + (size_t)DD * DD, nullptr, DD);
    transpose_f2b<<<dim3(DD / 32, DD / 32), blk, 0, stream>>>(Wg, DD, WqkvT + (size_t)2 * DD * DD, nullptr, DD);
    transpose_f2b<<<dim3(DH1 / 32, DD / 32), blk, 0, stream>>>(iW1, DH1, iW1hiT, iW1loT, DD);
    transpose_f2b<<<dim3(DH2 / 32, DH1 / 32), blk, 0, stream>>>(iW2, DH2, iW2hiT, iW2loT, DH1);
    transpose_f2b<<<dim3(DH1 / 32, DD / 32), blk, 0, stream>>>(fW1, DH1, fW1hiT, nullptr, DD);
    transpose_f2b<<<dim3(DH2 / 32, DH1 / 32), blk, 0, stream>>>(fW2, DH2, fW2hiT, nullptr, DH1);

    // 2. head 1 (split-bf16 — G-cliff precision)
    gemm_bt<1, true, 64, 64><<<dim3(DH1 / 64, NT / 64), blk, 0, stream>>>(
        Xhi, Xlo, DD, iW1hiT, iW1loT, DD, H1hi, H1lo, nullptr, DH1, ib1, nullptr, nullptr, nullptr, DD, 0);
    gemm_bt<1, true, 64, 64><<<dim3(DH2 / 64, NT / 64), blk, 0, stream>>>(
        H1hi, H1lo, DH1, iW2hiT, iW2loT, DH1, H2hi, H2lo, nullptr, DH2, ib2, nullptr, nullptr, nullptr, DH1, 0);
    head_tail<<<dim3(NT / 64), blk, 0, stream>>>(H2hi, H2lo, iWh, ibh, gam, out, G);

    // 3. QKV projection (last reader of Xhi)
    gemm_bt<0, false, 128, 128><<<dim3(3 * DD / 128, NT / 128), blk, 0, stream>>>(
        Xhi, nullptr, DD, WqkvT, nullptr, DD, QKV, nullptr, nullptr, 3 * DD,
        nullptr, nullptr, nullptr, nullptr, DD, 0);
    transpose_b2b<<<dim3(DD / 32, NT / 32), blk, 0, stream>>>(QKV + 2 * DD, 3 * DD, VbT, NT);

    hipMemsetAsync(E, 0, (size_t)NT * 4, stream);
    hipMemsetAsync(T, 0, (size_t)NT * 4, stream);

    // 4. attention panels (4096 cols each); Wp clobbers region A (dead bufs)
    for (int p = 0; p < NPAN; ++p) {
        const bf* Kp = QKV + (size_t)p * PANEL * (3 * DD) + DD;
        gemm_bt<2, false, 128, 128><<<dim3(PANEL / 128, NT / 128), blk, 0, stream>>>(
            QKV, nullptr, 3 * DD, Kp, nullptr, 3 * DD, Wp, nullptr, nullptr, PANEL,
            nullptr, G + p * PANEL, E, T, DD, 0);
        gemm_bt<3, false, 128, 64><<<dim3(DD / 64, NT / 128), blk, 0, stream>>>(
            Wp, nullptr, PANEL, VbT + p * PANEL, nullptr, NT, nullptr, nullptr, Macc, DD,
            nullptr, nullptr, nullptr, nullptr, PANEL, p > 0 ? 1 : 0);
    }

    // 5. Y = X + gelu(alpha*Macc + bg)
    fuse_y<<<dim3(NT * DD / 256), blk, 0, stream>>>(X, Macc, G, E, T, bg, Yhi);

    // 6. head 2 — plain bf16 (smooth outputs, threshold has 7x margin)
    gemm_bt<1, false, 64, 64><<<dim3(DH1 / 64, NT / 64), blk, 0, stream>>>(
        Yhi, nullptr, DD, fW1hiT, nullptr, DD, H1hi, nullptr, nullptr, DH1, fb1, nullptr, nullptr, nullptr, DD, 0);
    gemm_bt<1, false, 64, 64><<<dim3(DH2 / 64, NT / 64), blk, 0, stream>>>(
        H1hi, nullptr, DH1, fW2hiT, nullptr, DH1, H2hi, nullptr, nullptr, DH2, fb2, nullptr, nullptr, nullptr, DH1, 0);
    head_tail<<<dim3(NT / 64), blk, 0, stream>>>(H2hi, nullptr, fWh, fbh, gam, out + 4 * NT, nullptr);
}

// Round 7
// 561.624 us; speedup vs baseline: 1.3052x; 1.2017x over previous
//
#include <hip/hip_runtime.h>
#include <hip/hip_bf16.h>
#include <hip/hip_fp8.h>
#include <math.h>
#include <stdint.h>
#include <stddef.h>

// ---------------------------------------------------------------------------
// MetaEvidentialGSL: N=8192, D=768, H1=512, H2=256
// R2: XOR swizzle -> 0 bank conflicts. R4: dbuf + raw vmcnt barrier.
// R5: XCD-aware remap (PV fetch 297->~80 MB). R6: head2 plain bf16.
// R7: attention GEMMs in fp8 e4m3 (QK^T and PV): BK=64 at the same 16KB/iter
//     staging -> half the barrier iterations, 2x MFMA per barrier. QKV GEMM
//     epilogue emits fp8 directly; V^T via byte transpose. Head1 stays
//     split-bf16 (G-cliff); head2 plain bf16.
// ---------------------------------------------------------------------------

#define NT    8192
#define DD    768
#define DH1   512
#define DH2   256
#define PANEL 4096
#define NPAN  (NT / PANEL)

typedef __attribute__((ext_vector_type(8))) short  short8;
typedef __attribute__((ext_vector_type(4))) float  f32x4;
typedef __attribute__((ext_vector_type(2))) long   longx2;

#define MFMA16(a, b, c) __builtin_amdgcn_mfma_f32_16x16x32_bf16((a), (b), (c), 0, 0, 0)
#define MFMAF8(a, b, c) __builtin_amdgcn_mfma_f32_16x16x32_fp8_fp8((a), (b), (c), 0, 0, 0)

__device__ __forceinline__ float bf2f(__hip_bfloat16 x) { return __bfloat162float(x); }
__device__ __forceinline__ __hip_bfloat16 f2bf(float x) { return __float2bfloat16(x); }
__device__ __forceinline__ uint8_t f2fp8(float x) { return __hip_fp8_e4m3(x).__x; }

__device__ __forceinline__ float gelu_f(float x) {
    return 0.5f * x * (1.0f + erff(x * 0.7071067811865476f));
}
__device__ __forceinline__ float softplus_f(float x) {
    return (x > 20.0f) ? x : log1pf(expf(x));
}

// async 16B/lane global->LDS. LDS dest must be wave-uniform base + lane*16.
__device__ __forceinline__ void gload16(const void* g, void* l) {
    __builtin_amdgcn_global_load_lds(
        (const __attribute__((address_space(1))) void*)g,
        (__attribute__((address_space(3))) void*)l, 16, 0, 0);
}

// wait until <=N vm ops outstanding, then barrier.
template <int N>
__device__ __forceinline__ void wait_barrier() {
    asm volatile("s_waitcnt vmcnt(%0)\n\ts_barrier" :: "i"(N) : "memory");
}
__device__ __forceinline__ void plain_barrier() {
    asm volatile("s_barrier" ::: "memory");
}

// XCD-aware remap: linear workgroup id round-robins across 8 XCDs (id % 8).
// Remap so all column-blocks of one A row-panel share an XCD.
__device__ __forceinline__ void xcd_remap(int& bx, int& by) {
    const int nbx = gridDim.x, nby = gridDim.y;
    if ((nby & 7) == 0) {
        const int lin = by * nbx + bx;
        const int x   = lin & 7;
        const int s   = lin >> 3;
        bx = s % nbx;
        by = x + 8 * (s / nbx);
    }
}

// ---------------------------------------------------------------------------
// bf16 GEMM (heads + QKV): C(MxN) = A @ Bt^T. BK=32, triple-buffered.
// EPI: 0 = store bf16 (obf_hi) and/or fp8 (of8); 1 = bias+gelu -> bf16 (+lo)
// ---------------------------------------------------------------------------
template <int EPI, bool SPLIT, int TM, int TN>
__global__ __launch_bounds__(256)
void gemm_bt(const __hip_bfloat16* __restrict__ Ahi, const __hip_bfloat16* __restrict__ Alo, int lda,
             const __hip_bfloat16* __restrict__ Bhi, const __hip_bfloat16* __restrict__ Blo, int ldb,
             __hip_bfloat16* __restrict__ obf_hi, __hip_bfloat16* __restrict__ obf_lo,
             uint8_t* __restrict__ of8, int ldc,
             const float* __restrict__ bias, int K)
{
    constexpr int NB  = SPLIT ? 2 : 1;
    constexpr int WRM = (TM == 128 && TN == 128) ? 2 : (TM == 128 ? 4 : 2);
    constexpr int WCN = 4 / WRM;
    constexpr int WTM = TM / WRM;
    constexpr int WTN = TN / WCN;
    constexpr int MI  = WTM / 16;
    constexpr int NI  = WTN / 16;
    constexpr int PA  = TM / 64;
    constexpr int PB  = TN / 64;
    constexpr int LPI = (PA + PB) * NB;

    __shared__ __align__(16) __hip_bfloat16 As[NB][3][TM * 32];
    __shared__ __align__(16) __hip_bfloat16 Bs[NB][3][TN * 32];

    const int tid  = threadIdx.x;
    const int wave = tid >> 6;
    const int lane = tid & 63;
    int bx = blockIdx.x, by = blockIdx.y;
    xcd_remap(bx, by);
    const int tm = by * TM;
    const int tn = bx * TN;

    const int srow  = tid >> 2;
    const int sgcol = ((tid & 3) ^ ((srow >> 1) & 3)) * 8;
    const int lofs  = srow * 32 + (tid & 3) * 8;

    size_t aoffs[PA], boffs[PB];
#pragma unroll
    for (int p = 0; p < PA; ++p) aoffs[p] = (size_t)(tm + p * 64 + srow) * lda + sgcol;
#pragma unroll
    for (int p = 0; p < PB; ++p) boffs[p] = (size_t)(tn + p * 64 + srow) * ldb + sgcol;

    auto stage = [&](int k0, int buf) {
#pragma unroll
        for (int p = 0; p < PA; ++p)
            gload16(Ahi + aoffs[p] + k0, &As[0][buf][p * 2048 + lofs]);
#pragma unroll
        for (int p = 0; p < PB; ++p)
            gload16(Bhi + boffs[p] + k0, &Bs[0][buf][p * 2048 + lofs]);
        if constexpr (SPLIT) {
#pragma unroll
            for (int p = 0; p < PA; ++p)
                gload16(Alo + aoffs[p] + k0, &As[1][buf][p * 2048 + lofs]);
#pragma unroll
            for (int p = 0; p < PB; ++p)
                gload16(Blo + boffs[p] + k0, &Bs[1][buf][p * 2048 + lofs]);
        }
    };

    f32x4 acc[MI][NI];
#pragma unroll
    for (int i = 0; i < MI; ++i)
#pragma unroll
        for (int j = 0; j < NI; ++j) {
            f32x4 z = {0.0f, 0.0f, 0.0f, 0.0f};
            acc[i][j] = z;
        }

    const int wm   = (wave / WCN) * WTM;
    const int wn   = (wave % WCN) * WTN;
    const int l16  = lane & 15;
    const int quad = lane >> 4;
    const int rchunk = (quad ^ ((l16 >> 1) & 3)) * 8;
    const int arow0  = (wm + l16) * 32 + rchunk;
    const int brow0  = (wn + l16) * 32 + rchunk;

    const int nIter = K >> 5;
    stage(0, 0);
    if (nIter > 1) stage(32, 1);
    for (int k = 0; k < nIter; ++k) {
        const int cb = k % 3;
        if (k + 2 < nIter) {
            stage((k + 2) << 5, (k + 2) % 3);
            wait_barrier<2 * LPI>();
        } else if (k + 1 < nIter) {
            wait_barrier<LPI>();
        } else {
            wait_barrier<0>();
        }

        short8 ah[MI], bh[NI];
#pragma unroll
        for (int i = 0; i < MI; ++i) ah[i] = *(const short8*)&As[0][cb][arow0 + i * 512];
#pragma unroll
        for (int j = 0; j < NI; ++j) bh[j] = *(const short8*)&Bs[0][cb][brow0 + j * 512];
        if constexpr (SPLIT) {
            short8 al[MI], bl[NI];
#pragma unroll
            for (int i = 0; i < MI; ++i) al[i] = *(const short8*)&As[1][cb][arow0 + i * 512];
#pragma unroll
            for (int j = 0; j < NI; ++j) bl[j] = *(const short8*)&Bs[1][cb][brow0 + j * 512];
#pragma unroll
            for (int mi = 0; mi < MI; ++mi)
#pragma unroll
                for (int ni = 0; ni < NI; ++ni) {
                    acc[mi][ni] = MFMA16(ah[mi], bh[ni], acc[mi][ni]);
                    acc[mi][ni] = MFMA16(ah[mi], bl[ni], acc[mi][ni]);
                    acc[mi][ni] = MFMA16(al[mi], bh[ni], acc[mi][ni]);
                }
        } else {
#pragma unroll
            for (int mi = 0; mi < MI; ++mi)
#pragma unroll
                for (int ni = 0; ni < NI; ++ni)
                    acc[mi][ni] = MFMA16(ah[mi], bh[ni], acc[mi][ni]);
        }
        plain_barrier();
    }

    // C/D layout: col = lane&15, row = (lane>>4)*4 + reg  [verified m89/m91]
    const int rbase = tm + wm + quad * 4;
    const int cbase = tn + wn + l16;

    if constexpr (EPI == 0) {
#pragma unroll
        for (int mi = 0; mi < MI; ++mi)
#pragma unroll
            for (int ni = 0; ni < NI; ++ni) {
                f32x4 v = acc[mi][ni];
                const int col = cbase + ni * 16;
#pragma unroll
                for (int r = 0; r < 4; ++r) {
                    size_t idx = (size_t)(rbase + mi * 16 + r) * ldc + col;
                    if (obf_hi) obf_hi[idx] = f2bf(v[r]);
                    if (of8)    of8[idx]    = f2fp8(v[r]);
                }
            }
    } else {  // EPI == 1
#pragma unroll
        for (int mi = 0; mi < MI; ++mi)
#pragma unroll
            for (int ni = 0; ni < NI; ++ni) {
                f32x4 v = acc[mi][ni];
                const int col = cbase + ni * 16;
                const float b = bias[col];
#pragma unroll
                for (int r = 0; r < 4; ++r) {
                    float g = gelu_f(v[r] + b);
                    __hip_bfloat16 h = f2bf(g);
                    size_t idx = (size_t)(rbase + mi * 16 + r) * ldc + col;
                    obf_hi[idx] = h;
                    if (obf_lo) obf_lo[idx] = f2bf(g - bf2f(h));
                }
            }
    }
}

// ---------------------------------------------------------------------------
// fp8 GEMM (attention): C(MxN) = A(MxK) @ Bt(NxK)^T, all fp8 e4m3 inputs.
// BK=64 (64 B rows = 4 x 16 B chunks), triple-buffered, same byte-level XOR
// swizzle as the bf16 path (measured 0 conflicts): chunk c of row r at slot
// c ^ ((r>>1)&3); read-side XOR composes to identity (lane gets chunk=quad).
// Two MFMA k-halves per fragment pair (k-permutation identical for A and B).
// EPI: 2 = w=exp(acc/sqrt(D))*G[col] -> fp8, atomic rowsum E (exp) / T (w)
//      3 = fp32 store (accin=0) or accumulate (accin=1)
// ---------------------------------------------------------------------------
template <int EPI, int TM, int TN>
__global__ __launch_bounds__(256)
void gemm_f8(const uint8_t* __restrict__ A, int lda,
             const uint8_t* __restrict__ B, int ldb,
             uint8_t* __restrict__ of8, float* __restrict__ ofp, int ldc,
             const float* __restrict__ Gv, float* __restrict__ Esum,
             float* __restrict__ Tsum, int K, int accin)
{
    constexpr int WRM = (TN == 128) ? 2 : 4;
    constexpr int WCN = 4 / WRM;
    constexpr int WTM = TM / WRM;
    constexpr int WTN = TN / WCN;
    constexpr int MI  = WTM / 16;
    constexpr int NI  = WTN / 16;
    constexpr int PA  = TM / 64;
    constexpr int PB  = TN / 64;
    constexpr int LPI = PA + PB;

    __shared__ __align__(16) uint8_t As[3][TM * 64];
    __shared__ __align__(16) uint8_t Bs[3][TN * 64];

    const int tid  = threadIdx.x;
    const int wave = tid >> 6;
    const int lane = tid & 63;
    int bx = blockIdx.x, by = blockIdx.y;
    xcd_remap(bx, by);
    const int tm = by * TM;
    const int tn = bx * TN;

    // staging: thread row = tid>>2 (64 rows/pass), chunk = tid&3 (16 B).
    const int srow  = tid >> 2;
    const int sgcol = ((tid & 3) ^ ((srow >> 1) & 3)) * 16;   // byte col
    const int lofs  = tid * 16;

    size_t aoffs[PA], boffs[PB];
#pragma unroll
    for (int p = 0; p < PA; ++p) aoffs[p] = (size_t)(tm + p * 64 + srow) * lda + sgcol;
#pragma unroll
    for (int p = 0; p < PB; ++p) boffs[p] = (size_t)(tn + p * 64 + srow) * ldb + sgcol;

    auto stage = [&](int k0, int buf) {
#pragma unroll
        for (int p = 0; p < PA; ++p)
            gload16(A + aoffs[p] + k0, &As[buf][p * 4096 + lofs]);
#pragma unroll
        for (int p = 0; p < PB; ++p)
            gload16(B + boffs[p] + k0, &Bs[buf][p * 4096 + lofs]);
    };

    f32x4 acc[MI][NI];
#pragma unroll
    for (int i = 0; i < MI; ++i)
#pragma unroll
        for (int j = 0; j < NI; ++j) {
            f32x4 z = {0.0f, 0.0f, 0.0f, 0.0f};
            acc[i][j] = z;
        }

    const int wm   = (wave / WCN) * WTM;
    const int wn   = (wave % WCN) * WTN;
    const int l16  = lane & 15;
    const int quad = lane >> 4;
    const int rchunk = (quad ^ ((l16 >> 1) & 3)) * 16;   // byte chunk
    const int arow0  = (wm + l16) * 64 + rchunk;
    const int brow0  = (wn + l16) * 64 + rchunk;

    const int nIter = K >> 6;
    stage(0, 0);
    if (nIter > 1) stage(64, 1);
    for (int k = 0; k < nIter; ++k) {
        const int cb = k % 3;
        if (k + 2 < nIter) {
            stage((k + 2) << 6, (k + 2) % 3);
            wait_barrier<2 * LPI>();
        } else if (k + 1 < nIter) {
            wait_barrier<LPI>();
        } else {
            wait_barrier<0>();
        }

        longx2 a[MI], b[NI];
#pragma unroll
        for (int i = 0; i < MI; ++i) a[i] = *(const longx2*)&As[cb][arow0 + i * 1024];
#pragma unroll
        for (int j = 0; j < NI; ++j) b[j] = *(const longx2*)&Bs[cb][brow0 + j * 1024];
#pragma unroll
        for (int mi = 0; mi < MI; ++mi)
#pragma unroll
            for (int ni = 0; ni < NI; ++ni) {
                acc[mi][ni] = MFMAF8(a[mi][0], b[ni][0], acc[mi][ni]);
                acc[mi][ni] = MFMAF8(a[mi][1], b[ni][1], acc[mi][ni]);
            }
        plain_barrier();
    }

    const int rbase = tm + wm + quad * 4;
    const int cbase = tn + wn + l16;

    if constexpr (EPI == 2) {
        const float SCL = 0.03608439182435161f;   // 1/sqrt(768)
#pragma unroll
        for (int mi = 0; mi < MI; ++mi) {
            float sE[4] = {0.f, 0.f, 0.f, 0.f};
            float sT[4] = {0.f, 0.f, 0.f, 0.f};
#pragma unroll
            for (int ni = 0; ni < NI; ++ni) {
                f32x4 v = acc[mi][ni];
                const int col = cbase + ni * 16;
                const float g = Gv[col];
#pragma unroll
                for (int r = 0; r < 4; ++r) {
                    float we = __expf(v[r] * SCL);
                    float w  = we * g;
                    of8[(size_t)(rbase + mi * 16 + r) * ldc + col] = f2fp8(w);
                    sE[r] += we;
                    sT[r] += w;
                }
            }
#pragma unroll
            for (int st = 1; st < 16; st <<= 1)
#pragma unroll
                for (int r = 0; r < 4; ++r) {
                    sE[r] += __shfl_xor(sE[r], st);
                    sT[r] += __shfl_xor(sT[r], st);
                }
            if (l16 == 0) {
#pragma unroll
                for (int r = 0; r < 4; ++r) {
                    atomicAdd(&Esum[rbase + mi * 16 + r], sE[r]);
                    atomicAdd(&Tsum[rbase + mi * 16 + r], sT[r]);
                }
            }
        }
    } else {  // EPI == 3
#pragma unroll
        for (int mi = 0; mi < MI; ++mi)
#pragma unroll
            for (int ni = 0; ni < NI; ++ni) {
                f32x4 v = acc[mi][ni];
                const int col = cbase + ni * 16;
#pragma unroll
                for (int r = 0; r < 4; ++r) {
                    size_t idx = (size_t)(rbase + mi * 16 + r) * ldc + col;
                    if (accin) ofp[idx] += v[r];
                    else       ofp[idx]  = v[r];
                }
            }
    }
}

// ---------------------------------------------------------------------------
__global__ __launch_bounds__(256)
void transpose_f2b(const float* __restrict__ in, int ldin,
                   __hip_bfloat16* __restrict__ ohi, __hip_bfloat16* __restrict__ olo, int ldout)
{
    __shared__ float t[32][33];
    const int tx = threadIdx.x & 31;
    const int ty = threadIdx.x >> 5;
    const int r0 = blockIdx.y * 32;
    const int c0 = blockIdx.x * 32;
#pragma unroll
    for (int j = 0; j < 32; j += 8)
        t[ty + j][tx] = in[(size_t)(r0 + ty + j) * ldin + c0 + tx];
    __syncthreads();
#pragma unroll
    for (int j = 0; j < 32; j += 8) {
        float x = t[tx][ty + j];
        __hip_bfloat16 h = f2bf(x);
        size_t o = (size_t)(c0 + ty + j) * ldout + r0 + tx;
        ohi[o] = h;
        if (olo) olo[o] = f2bf(x - bf2f(h));
    }
}

// fp8 -> fp8 byte transpose (V part of QKVf8 -> VTf8)
__global__ __launch_bounds__(256)
void transpose_f8(const uint8_t* __restrict__ in, int ldin,
                  uint8_t* __restrict__ out, int ldout)
{
    __shared__ uint8_t t[32][33];
    const int tx = threadIdx.x & 31;
    const int ty = threadIdx.x >> 5;
    const int r0 = blockIdx.y * 32;
    const int c0 = blockIdx.x * 32;
#pragma unroll
    for (int j = 0; j < 32; j += 8)
        t[ty + j][tx] = in[(size_t)(r0 + ty + j) * ldin + c0 + tx];
    __syncthreads();
#pragma unroll
    for (int j = 0; j < 32; j += 8)
        out[(size_t)(c0 + ty + j) * ldout + r0 + tx] = t[tx][ty + j];
}

__global__ __launch_bounds__(256)
void cvt_split(const float* __restrict__ in, __hip_bfloat16* __restrict__ hi,
               __hip_bfloat16* __restrict__ lo)
{
    const int i = (blockIdx.x * 256 + threadIdx.x) * 4;
    f32x4 v = *(const f32x4*)(in + i);
#pragma unroll
    for (int k = 0; k < 4; ++k) {
        __hip_bfloat16 h = f2bf(v[k]);
        hi[i + k] = h;
        lo[i + k] = f2bf(v[k] - bf2f(h));
    }
}

// ---------------------------------------------------------------------------
// head tail: r = H2 @ Wh + bh (fp32; hi + optional lo), NIG transforms, opt G.
// ---------------------------------------------------------------------------
__global__ __launch_bounds__(256)
void head_tail(const __hip_bfloat16* __restrict__ H2hi, const __hip_bfloat16* __restrict__ H2lo,
               const float* __restrict__ Wh, const float* __restrict__ bh,
               const float* __restrict__ gamp,
               float* __restrict__ outBase, float* __restrict__ Gout)
{
    __shared__ float sa[64], sb[64];
    const int tid = threadIdx.x;
    const int rl  = tid >> 2;
    const int c   = tid & 3;
    const int row = blockIdx.x * 64 + rl;
    const __hip_bfloat16* hh = H2hi + (size_t)row * DH2;
    const __hip_bfloat16* hl = H2lo ? H2lo + (size_t)row * DH2 : nullptr;
    float acc = bh[c];
    if (hl) {
        for (int k = 0; k < DH2; ++k)
            acc = fmaf(bf2f(hh[k]) + bf2f(hl[k]), Wh[k * 4 + c], acc);
    } else {
        for (int k = 0; k < DH2; ++k)
            acc = fmaf(bf2f(hh[k]), Wh[k * 4 + c], acc);
    }
    float sp = softplus_f(acc);
    if (c == 0) {
        outBase[row] = acc;                        // mu
    } else if (c == 1) {
        outBase[NT + row] = sp + 1e-6f;            // v
    } else if (c == 2) {
        float a0 = (sp + 1.0f) + 1e-6f;            // match ref assoc order
        outBase[2 * NT + row] = a0;
        if (Gout) sa[rl] = a0 - 1.0f;
    } else {
        float b0 = sp + 1e-6f;
        outBase[3 * NT + row] = b0;
        if (Gout) sb[rl] = b0;
    }
    if (Gout != nullptr) {
        __syncthreads();
        if (c == 0) {
            float u   = sb[rl] / fmaxf(sa[rl], 1e-8f);
            float sig = 1.0f / (1.0f + expf(-u));
            Gout[row] = 1.0f - gamp[0] * sig;
        }
    }
}

// ---------------------------------------------------------------------------
// Y = X + gelu(alpha*Macc + bg); alpha = G/(E*max(G*T/E,1e-8))
// ---------------------------------------------------------------------------
__global__ __launch_bounds__(256)
void fuse_y(const float* __restrict__ X, const float* __restrict__ Macc,
            const float* __restrict__ G, const float* __restrict__ E,
            const float* __restrict__ T, const float* __restrict__ bg,
            __hip_bfloat16* __restrict__ Yhi)
{
    const int i   = blockIdx.x * 256 + threadIdx.x;
    const int row = i / DD;
    const int col = i - row * DD;
    const float g = G[row], e = E[row], t = T[row];
    const float denom = fmaxf(g * t / e, 1e-8f);
    const float alpha = g / (e * denom);
    const float m = alpha * Macc[i];
    Yhi[i] = f2bf(X[i] + gelu_f(m + bg[col]));
}

// ---------------------------------------------------------------------------
extern "C" void kernel_launch(void* const* d_in, const int* in_sizes, int n_in,
                              void* d_out, int out_size, void* d_ws, size_t ws_size,
                              hipStream_t stream)
{
    (void)in_sizes; (void)n_in; (void)out_size; (void)ws_size;
    const float* X   = (const float*)d_in[0];
    const float* Wq  = (const float*)d_in[1];
    const float* Wk  = (const float*)d_in[2];
    const float* Wg  = (const float*)d_in[3];
    const float* bg  = (const float*)d_in[4];
    const float* gam = (const float*)d_in[5];
    const float* iW1 = (const float*)d_in[6];
    const float* ib1 = (const float*)d_in[7];
    const float* iW2 = (const float*)d_in[8];
    const float* ib2 = (const float*)d_in[9];
    const float* iWh = (const float*)d_in[10];
    const float* ibh = (const float*)d_in[11];
    const float* fW1 = (const float*)d_in[12];
    const float* fb1 = (const float*)d_in[13];
    const float* fW2 = (const float*)d_in[14];
    const float* fb2 = (const float*)d_in[15];
    const float* fWh = (const float*)d_in[16];
    const float* fbh = (const float*)d_in[17];
    float* out = (float*)d_out;

    char* cur = (char*)d_ws;
    auto alloc = [&](size_t bytes) -> char* {
        char* p = cur;
        cur += (bytes + 255) & ~(size_t)255;
        return p;
    };
    typedef __hip_bfloat16 bf;

    // Region A: Wp fp8 (33.5 MB) aliased over attention-phase-dead buffers
    // (Xhi/Xlo 25.2 MB + H1/H2 25.2 MB; region sized by the old 50.3 MB max).
    char* regA = alloc((size_t)NT * DD * 4 + (size_t)NT * DH1 * 4 + (size_t)NT * DH2 * 4);
    uint8_t* Wp = (uint8_t*)regA;
    bf* Xhi  = (bf*)(regA);
    bf* Xlo  = (bf*)(regA + (size_t)NT * DD * 2);
    bf* H1hi = (bf*)(regA + (size_t)NT * DD * 4);
    bf* H1lo = (bf*)(regA + (size_t)NT * DD * 4 + (size_t)NT * DH1 * 2);
    bf* H2hi = (bf*)(regA + (size_t)NT * DD * 4 + (size_t)NT * DH1 * 4);
    bf* H2lo = (bf*)(regA + (size_t)NT * DD * 4 + (size_t)NT * DH1 * 4 + (size_t)NT * DH2 * 2);

    bf* WqkvT  = (bf*)alloc((size_t)3 * DD * DD * 2);
    bf* iW1hiT = (bf*)alloc((size_t)DH1 * DD * 2);
    bf* iW1loT = (bf*)alloc((size_t)DH1 * DD * 2);
    bf* iW2hiT = (bf*)alloc((size_t)DH2 * DH1 * 2);
    bf* iW2loT = (bf*)alloc((size_t)DH2 * DH1 * 2);
    bf* fW1hiT = (bf*)alloc((size_t)DH1 * DD * 2);
    bf* fW2hiT = (bf*)alloc((size_t)DH2 * DH1 * 2);
    uint8_t* QKVf8 = (uint8_t*)alloc((size_t)NT * 3 * DD);   // 8192 x 2304 fp8
    uint8_t* VTf8  = (uint8_t*)alloc((size_t)DD * NT);       // 768 x 8192 fp8
    float* G    = (float*)alloc((size_t)NT * 4);
    float* E    = (float*)alloc((size_t)NT * 4);
    float* T    = (float*)alloc((size_t)NT * 4);
    float* Macc = (float*)alloc((size_t)NT * DD * 4);
    bf* Yhi    = (bf*)alloc((size_t)NT * DD * 2);

    const dim3 blk(256);

    // 1. converts / transposes
    cvt_split<<<dim3(NT * DD / 1024), blk, 0, stream>>>(X, Xhi, Xlo);
    transpose_f2b<<<dim3(DD / 32, DD / 32), blk, 0, stream>>>(Wq, DD, WqkvT, nullptr, DD);
    transpose_f2b<<<dim3(DD / 32, DD / 32), blk, 0, stream>>>(Wk, DD, WqkvT + (size_t)DD * DD, nullptr, DD);
    transpose_f2b<<<dim3(DD / 32, DD / 32), blk, 0, stream>>>(Wg, DD, WqkvT + (size_t)2 * DD * DD, nullptr, DD);
    transpose_f2b<<<dim3(DH1 / 32, DD / 32), blk, 0, stream>>>(iW1, DH1, iW1hiT, iW1loT, DD);
    transpose_f2b<<<dim3(DH2 / 32, DH1 / 32), blk, 0, stream>>>(iW2, DH2, iW2hiT, iW2loT, DH1);
    transpose_f2b<<<dim3(DH1 / 32, DD / 32), blk, 0, stream>>>(fW1, DH1, fW1hiT, nullptr, DD);
    transpose_f2b<<<dim3(DH2 / 32, DH1 / 32), blk, 0, stream>>>(fW2, DH2, fW2hiT, nullptr, DH1);

    // 2. head 1 (split-bf16 — G-cliff precision)
    gemm_bt<1, true, 64, 64><<<dim3(DH1 / 64, NT / 64), blk, 0, stream>>>(
        Xhi, Xlo, DD, iW1hiT, iW1loT, DD, H1hi, H1lo, nullptr, DH1, ib1, DD);
    gemm_bt<1, true, 64, 64><<<dim3(DH2 / 64, NT / 64), blk, 0, stream>>>(
        H1hi, H1lo, DH1, iW2hiT, iW2loT, DH1, H2hi, H2lo, nullptr, DH2, ib2, DH1);
    head_tail<<<dim3(NT / 64), blk, 0, stream>>>(H2hi, H2lo, iWh, ibh, gam, out, G);

    // 3. QKV projection -> fp8 directly (last reader of Xhi)
    gemm_bt<0, false, 128, 128><<<dim3(3 * DD / 128, NT / 128), blk, 0, stream>>>(
        Xhi, nullptr, DD, WqkvT, nullptr, DD, nullptr, nullptr, QKVf8, 3 * DD,
        nullptr, DD);
    transpose_f8<<<dim3(DD / 32, NT / 32), blk, 0, stream>>>(QKVf8 + 2 * DD, 3 * DD, VTf8, NT);

    hipMemsetAsync(E, 0, (size_t)NT * 4, stream);
    hipMemsetAsync(T, 0, (size_t)NT * 4, stream);

    // 4. attention panels (4096 cols each), all-fp8; Wp clobbers region A
    for (int p = 0; p < NPAN; ++p) {
        const uint8_t* Kp = QKVf8 + (size_t)p * PANEL * (3 * DD) + DD;
        gemm_f8<2, 128, 128><<<dim3(PANEL / 128, NT / 128), blk, 0, stream>>>(
            QKVf8, 3 * DD, Kp, 3 * DD, Wp, nullptr, PANEL,
            G + p * PANEL, E, T, DD, 0);
        gemm_f8<3, 128, 64><<<dim3(DD / 64, NT / 128), blk, 0, stream>>>(
            Wp, PANEL, VTf8 + (size_t)p * PANEL, NT, nullptr, Macc, DD,
            nullptr, nullptr, nullptr, PANEL, p > 0 ? 1 : 0);
    }

    // 5. Y = X + gelu(alpha*Macc + bg)
    fuse_y<<<dim3(NT * DD / 256), blk, 0, stream>>>(X, Macc, G, E, T, bg, Yhi);

    // 6. head 2 — plain bf16 (smooth outputs, ample threshold margin)
    gemm_bt<1, false, 64, 64><<<dim3(DH1 / 64, NT / 64), blk, 0, stream>>>(
        Yhi, nullptr, DD, fW1hiT, nullptr, DD, H1hi, nullptr, nullptr, DH1, fb1, DD);
    gemm_bt<1, false, 64, 64><<<dim3(DH2 / 64, NT / 64), blk, 0, stream>>>(
        H1hi, nullptr, DH1, fW2hiT, nullptr, DH1, H2hi, nullptr, nullptr, DH2, fb2, DH1);
    head_tail<<<dim3(NT / 64), blk, 0, stream>>>(H2hi, nullptr, fWh, fbh, gam, out + 4 * NT, nullptr);
}

// Round 8
// 550.589 us; speedup vs baseline: 1.3313x; 1.0200x over previous
//
#include <hip/hip_runtime.h>
#include <hip/hip_bf16.h>
#include <hip/hip_fp8.h>
#include <math.h>
#include <stdint.h>
#include <stddef.h>

// ---------------------------------------------------------------------------
// MetaEvidentialGSL: N=8192, D=768, H1=512, H2=256
// R2: XOR swizzle -> 0 conflicts. R4: dbuf + raw vmcnt barrier. R5: XCD
// remap. R6: head2 plain bf16. R7: fp8 attention (BK=64). 562 us.
// R8: PANEL=8192 -> PV is ONE dispatch with K=8192 (128-iter long loop);
//     PV epilogue fuses Y = X + gelu(alpha*acc + bg) (Macc eliminated);
//     double-buffer everywhere (32 KB LDS -> 4 resident blocks vs 3).
// ---------------------------------------------------------------------------

#define NT    8192
#define DD    768
#define DH1   512
#define DH2   256

typedef __attribute__((ext_vector_type(8))) short  short8;
typedef __attribute__((ext_vector_type(4))) float  f32x4;
typedef __attribute__((ext_vector_type(2))) long   longx2;

#define MFMA16(a, b, c) __builtin_amdgcn_mfma_f32_16x16x32_bf16((a), (b), (c), 0, 0, 0)
#define MFMAF8(a, b, c) __builtin_amdgcn_mfma_f32_16x16x32_fp8_fp8((a), (b), (c), 0, 0, 0)

__device__ __forceinline__ float bf2f(__hip_bfloat16 x) { return __bfloat162float(x); }
__device__ __forceinline__ __hip_bfloat16 f2bf(float x) { return __float2bfloat16(x); }
__device__ __forceinline__ uint8_t f2fp8(float x) { return __hip_fp8_e4m3(x).__x; }

__device__ __forceinline__ float gelu_f(float x) {
    return 0.5f * x * (1.0f + erff(x * 0.7071067811865476f));
}
__device__ __forceinline__ float softplus_f(float x) {
    return (x > 20.0f) ? x : log1pf(expf(x));
}

// async 16B/lane global->LDS. LDS dest must be wave-uniform base + lane*16.
__device__ __forceinline__ void gload16(const void* g, void* l) {
    __builtin_amdgcn_global_load_lds(
        (const __attribute__((address_space(1))) void*)g,
        (__attribute__((address_space(3))) void*)l, 16, 0, 0);
}

// wait until <=N vm ops outstanding, then barrier.
template <int N>
__device__ __forceinline__ void wait_barrier() {
    asm volatile("s_waitcnt vmcnt(%0)\n\ts_barrier" :: "i"(N) : "memory");
}
__device__ __forceinline__ void plain_barrier() {
    asm volatile("s_barrier" ::: "memory");
}

// XCD-aware remap: linear workgroup id round-robins across 8 XCDs (id % 8).
__device__ __forceinline__ void xcd_remap(int& bx, int& by) {
    const int nbx = gridDim.x, nby = gridDim.y;
    if ((nby & 7) == 0) {
        const int lin = by * nbx + bx;
        const int x   = lin & 7;
        const int s   = lin >> 3;
        bx = s % nbx;
        by = x + 8 * (s / nbx);
    }
}

// ---------------------------------------------------------------------------
// bf16 GEMM (heads + QKV): C(MxN) = A @ Bt^T. BK=32, double-buffered.
// EPI: 0 = store bf16 (obf_hi) and/or fp8 (of8); 1 = bias+gelu -> bf16 (+lo)
// ---------------------------------------------------------------------------
template <int EPI, bool SPLIT, int TM, int TN>
__global__ __launch_bounds__(256)
void gemm_bt(const __hip_bfloat16* __restrict__ Ahi, const __hip_bfloat16* __restrict__ Alo, int lda,
             const __hip_bfloat16* __restrict__ Bhi, const __hip_bfloat16* __restrict__ Blo, int ldb,
             __hip_bfloat16* __restrict__ obf_hi, __hip_bfloat16* __restrict__ obf_lo,
             uint8_t* __restrict__ of8, int ldc,
             const float* __restrict__ bias, int K)
{
    constexpr int NB  = SPLIT ? 2 : 1;
    constexpr int WRM = (TM == 128 && TN == 128) ? 2 : (TM == 128 ? 4 : 2);
    constexpr int WCN = 4 / WRM;
    constexpr int WTM = TM / WRM;
    constexpr int WTN = TN / WCN;
    constexpr int MI  = WTM / 16;
    constexpr int NI  = WTN / 16;
    constexpr int PA  = TM / 64;
    constexpr int PB  = TN / 64;
    constexpr int LPI = (PA + PB) * NB;

    __shared__ __align__(16) __hip_bfloat16 As[NB][2][TM * 32];
    __shared__ __align__(16) __hip_bfloat16 Bs[NB][2][TN * 32];

    const int tid  = threadIdx.x;
    const int wave = tid >> 6;
    const int lane = tid & 63;
    int bx = blockIdx.x, by = blockIdx.y;
    xcd_remap(bx, by);
    const int tm = by * TM;
    const int tn = bx * TN;

    const int srow  = tid >> 2;
    const int sgcol = ((tid & 3) ^ ((srow >> 1) & 3)) * 8;
    const int lofs  = srow * 32 + (tid & 3) * 8;

    size_t aoffs[PA], boffs[PB];
#pragma unroll
    for (int p = 0; p < PA; ++p) aoffs[p] = (size_t)(tm + p * 64 + srow) * lda + sgcol;
#pragma unroll
    for (int p = 0; p < PB; ++p) boffs[p] = (size_t)(tn + p * 64 + srow) * ldb + sgcol;

    auto stage = [&](int k0, int buf) {
#pragma unroll
        for (int p = 0; p < PA; ++p)
            gload16(Ahi + aoffs[p] + k0, &As[0][buf][p * 2048 + lofs]);
#pragma unroll
        for (int p = 0; p < PB; ++p)
            gload16(Bhi + boffs[p] + k0, &Bs[0][buf][p * 2048 + lofs]);
        if constexpr (SPLIT) {
#pragma unroll
            for (int p = 0; p < PA; ++p)
                gload16(Alo + aoffs[p] + k0, &As[1][buf][p * 2048 + lofs]);
#pragma unroll
            for (int p = 0; p < PB; ++p)
                gload16(Blo + boffs[p] + k0, &Bs[1][buf][p * 2048 + lofs]);
        }
    };

    f32x4 acc[MI][NI];
#pragma unroll
    for (int i = 0; i < MI; ++i)
#pragma unroll
        for (int j = 0; j < NI; ++j) {
            f32x4 z = {0.0f, 0.0f, 0.0f, 0.0f};
            acc[i][j] = z;
        }

    const int wm   = (wave / WCN) * WTM;
    const int wn   = (wave % WCN) * WTN;
    const int l16  = lane & 15;
    const int quad = lane >> 4;
    const int rchunk = (quad ^ ((l16 >> 1) & 3)) * 8;
    const int arow0  = (wm + l16) * 32 + rchunk;
    const int brow0  = (wn + l16) * 32 + rchunk;

    const int nIter = K >> 5;
    stage(0, 0);
    for (int k = 0; k < nIter; ++k) {
        const int cb = k & 1;
        if (k + 1 < nIter) {
            stage((k + 1) << 5, cb ^ 1);
            wait_barrier<LPI>();
        } else {
            wait_barrier<0>();
        }

        short8 ah[MI], bh[NI];
#pragma unroll
        for (int i = 0; i < MI; ++i) ah[i] = *(const short8*)&As[0][cb][arow0 + i * 512];
#pragma unroll
        for (int j = 0; j < NI; ++j) bh[j] = *(const short8*)&Bs[0][cb][brow0 + j * 512];
        if constexpr (SPLIT) {
            short8 al[MI], bl[NI];
#pragma unroll
            for (int i = 0; i < MI; ++i) al[i] = *(const short8*)&As[1][cb][arow0 + i * 512];
#pragma unroll
            for (int j = 0; j < NI; ++j) bl[j] = *(const short8*)&Bs[1][cb][brow0 + j * 512];
#pragma unroll
            for (int mi = 0; mi < MI; ++mi)
#pragma unroll
                for (int ni = 0; ni < NI; ++ni) {
                    acc[mi][ni] = MFMA16(ah[mi], bh[ni], acc[mi][ni]);
                    acc[mi][ni] = MFMA16(ah[mi], bl[ni], acc[mi][ni]);
                    acc[mi][ni] = MFMA16(al[mi], bh[ni], acc[mi][ni]);
                }
        } else {
#pragma unroll
            for (int mi = 0; mi < MI; ++mi)
#pragma unroll
                for (int ni = 0; ni < NI; ++ni)
                    acc[mi][ni] = MFMA16(ah[mi], bh[ni], acc[mi][ni]);
        }
        plain_barrier();
    }

    // C/D layout: col = lane&15, row = (lane>>4)*4 + reg  [verified m89/m91]
    const int rbase = tm + wm + quad * 4;
    const int cbase = tn + wn + l16;

    if constexpr (EPI == 0) {
#pragma unroll
        for (int mi = 0; mi < MI; ++mi)
#pragma unroll
            for (int ni = 0; ni < NI; ++ni) {
                f32x4 v = acc[mi][ni];
                const int col = cbase + ni * 16;
#pragma unroll
                for (int r = 0; r < 4; ++r) {
                    size_t idx = (size_t)(rbase + mi * 16 + r) * ldc + col;
                    if (obf_hi) obf_hi[idx] = f2bf(v[r]);
                    if (of8)    of8[idx]    = f2fp8(v[r]);
                }
            }
    } else {  // EPI == 1
#pragma unroll
        for (int mi = 0; mi < MI; ++mi)
#pragma unroll
            for (int ni = 0; ni < NI; ++ni) {
                f32x4 v = acc[mi][ni];
                const int col = cbase + ni * 16;
                const float b = bias[col];
#pragma unroll
                for (int r = 0; r < 4; ++r) {
                    float g = gelu_f(v[r] + b);
                    __hip_bfloat16 h = f2bf(g);
                    size_t idx = (size_t)(rbase + mi * 16 + r) * ldc + col;
                    obf_hi[idx] = h;
                    if (obf_lo) obf_lo[idx] = f2bf(g - bf2f(h));
                }
            }
    }
}

// ---------------------------------------------------------------------------
// fp8 GEMM (attention): C(MxN) = A(MxK) @ Bt(NxK)^T, fp8 e4m3 inputs.
// BK=64, double-buffered, byte-level XOR swizzle (0 conflicts).
// EPI: 2 = w=exp(acc/sqrt(D))*G[col] -> fp8, atomic rowsum E (exp) / T (w)
//      4 = fused Y epilogue: Y = X + gelu(alpha*acc + bg),
//          alpha = G/(E*max(G*T/E,1e-8))   (exact reference clamp semantics)
// ---------------------------------------------------------------------------
template <int EPI, int TM, int TN>
__global__ __launch_bounds__(256)
void gemm_f8(const uint8_t* __restrict__ A, int lda,
             const uint8_t* __restrict__ B, int ldb,
             uint8_t* __restrict__ of8, int ldc,
             const float* __restrict__ Gv, float* __restrict__ Esum,
             float* __restrict__ Tsum,
             const float* __restrict__ Xf, const float* __restrict__ bg2,
             const float* __restrict__ Grow, const float* __restrict__ Erow,
             const float* __restrict__ Trow,
             __hip_bfloat16* __restrict__ Yout, int K)
{
    constexpr int WRM = (TN == 128) ? 2 : 4;
    constexpr int WCN = 4 / WRM;
    constexpr int WTM = TM / WRM;
    constexpr int WTN = TN / WCN;
    constexpr int MI  = WTM / 16;
    constexpr int NI  = WTN / 16;
    constexpr int PA  = TM / 64;
    constexpr int PB  = TN / 64;
    constexpr int LPI = PA + PB;

    __shared__ __align__(16) uint8_t As[2][TM * 64];
    __shared__ __align__(16) uint8_t Bs[2][TN * 64];

    const int tid  = threadIdx.x;
    const int wave = tid >> 6;
    const int lane = tid & 63;
    int bx = blockIdx.x, by = blockIdx.y;
    xcd_remap(bx, by);
    const int tm = by * TM;
    const int tn = bx * TN;

    const int srow  = tid >> 2;
    const int sgcol = ((tid & 3) ^ ((srow >> 1) & 3)) * 16;   // byte col
    const int lofs  = tid * 16;

    size_t aoffs[PA], boffs[PB];
#pragma unroll
    for (int p = 0; p < PA; ++p) aoffs[p] = (size_t)(tm + p * 64 + srow) * lda + sgcol;
#pragma unroll
    for (int p = 0; p < PB; ++p) boffs[p] = (size_t)(tn + p * 64 + srow) * ldb + sgcol;

    auto stage = [&](int k0, int buf) {
#pragma unroll
        for (int p = 0; p < PA; ++p)
            gload16(A + aoffs[p] + k0, &As[buf][p * 4096 + lofs]);
#pragma unroll
        for (int p = 0; p < PB; ++p)
            gload16(B + boffs[p] + k0, &Bs[buf][p * 4096 + lofs]);
    };

    f32x4 acc[MI][NI];
#pragma unroll
    for (int i = 0; i < MI; ++i)
#pragma unroll
        for (int j = 0; j < NI; ++j) {
            f32x4 z = {0.0f, 0.0f, 0.0f, 0.0f};
            acc[i][j] = z;
        }

    const int wm   = (wave / WCN) * WTM;
    const int wn   = (wave % WCN) * WTN;
    const int l16  = lane & 15;
    const int quad = lane >> 4;
    const int rchunk = (quad ^ ((l16 >> 1) & 3)) * 16;
    const int arow0  = (wm + l16) * 64 + rchunk;
    const int brow0  = (wn + l16) * 64 + rchunk;

    const int nIter = K >> 6;
    stage(0, 0);
    for (int k = 0; k < nIter; ++k) {
        const int cb = k & 1;
        if (k + 1 < nIter) {
            stage((k + 1) << 6, cb ^ 1);
            wait_barrier<LPI>();
        } else {
            wait_barrier<0>();
        }

        longx2 a[MI], b[NI];
#pragma unroll
        for (int i = 0; i < MI; ++i) a[i] = *(const longx2*)&As[cb][arow0 + i * 1024];
#pragma unroll
        for (int j = 0; j < NI; ++j) b[j] = *(const longx2*)&Bs[cb][brow0 + j * 1024];
#pragma unroll
        for (int mi = 0; mi < MI; ++mi)
#pragma unroll
            for (int ni = 0; ni < NI; ++ni) {
                acc[mi][ni] = MFMAF8(a[mi][0], b[ni][0], acc[mi][ni]);
                acc[mi][ni] = MFMAF8(a[mi][1], b[ni][1], acc[mi][ni]);
            }
        plain_barrier();
    }

    const int rbase = tm + wm + quad * 4;
    const int cbase = tn + wn + l16;

    if constexpr (EPI == 2) {
        const float SCL = 0.03608439182435161f;   // 1/sqrt(768)
#pragma unroll
        for (int mi = 0; mi < MI; ++mi) {
            float sE[4] = {0.f, 0.f, 0.f, 0.f};
            float sT[4] = {0.f, 0.f, 0.f, 0.f};
#pragma unroll
            for (int ni = 0; ni < NI; ++ni) {
                f32x4 v = acc[mi][ni];
                const int col = cbase + ni * 16;
                const float g = Gv[col];
#pragma unroll
                for (int r = 0; r < 4; ++r) {
                    float we = __expf(v[r] * SCL);
                    float w  = we * g;
                    of8[(size_t)(rbase + mi * 16 + r) * ldc + col] = f2fp8(w);
                    sE[r] += we;
                    sT[r] += w;
                }
            }
#pragma unroll
            for (int st = 1; st < 16; st <<= 1)
#pragma unroll
                for (int r = 0; r < 4; ++r) {
                    sE[r] += __shfl_xor(sE[r], st);
                    sT[r] += __shfl_xor(sT[r], st);
                }
            if (l16 == 0) {
#pragma unroll
                for (int r = 0; r < 4; ++r) {
                    atomicAdd(&Esum[rbase + mi * 16 + r], sE[r]);
                    atomicAdd(&Tsum[rbase + mi * 16 + r], sT[r]);
                }
            }
        }
    } else {  // EPI == 4: fused Y = X + gelu(alpha*acc + bg)
#pragma unroll
        for (int mi = 0; mi < MI; ++mi) {
#pragma unroll
            for (int r = 0; r < 4; ++r) {
                const int row = rbase + mi * 16 + r;
                const float g = Grow[row], e = Erow[row], t = Trow[row];
                const float denom = fmaxf(g * t / e, 1e-8f);
                const float alpha = g / (e * denom);
#pragma unroll
                for (int ni = 0; ni < NI; ++ni) {
                    const int col = cbase + ni * 16;
                    const float m = alpha * acc[mi][ni][r];
                    const size_t idx = (size_t)row * ldc + col;
                    Yout[idx] = f2bf(Xf[idx] + gelu_f(m + bg2[col]));
                }
            }
        }
    }
}

// ---------------------------------------------------------------------------
__global__ __launch_bounds__(256)
void transpose_f2b(const float* __restrict__ in, int ldin,
                   __hip_bfloat16* __restrict__ ohi, __hip_bfloat16* __restrict__ olo, int ldout)
{
    __shared__ float t[32][33];
    const int tx = threadIdx.x & 31;
    const int ty = threadIdx.x >> 5;
    const int r0 = blockIdx.y * 32;
    const int c0 = blockIdx.x * 32;
#pragma unroll
    for (int j = 0; j < 32; j += 8)
        t[ty + j][tx] = in[(size_t)(r0 + ty + j) * ldin + c0 + tx];
    __syncthreads();
#pragma unroll
    for (int j = 0; j < 32; j += 8) {
        float x = t[tx][ty + j];
        __hip_bfloat16 h = f2bf(x);
        size_t o = (size_t)(c0 + ty + j) * ldout + r0 + tx;
        ohi[o] = h;
        if (olo) olo[o] = f2bf(x - bf2f(h));
    }
}

// fp8 byte transpose (V part of QKVf8 -> VTf8)
__global__ __launch_bounds__(256)
void transpose_f8(const uint8_t* __restrict__ in, int ldin,
                  uint8_t* __restrict__ out, int ldout)
{
    __shared__ uint8_t t[32][33];
    const int tx = threadIdx.x & 31;
    const int ty = threadIdx.x >> 5;
    const int r0 = blockIdx.y * 32;
    const int c0 = blockIdx.x * 32;
#pragma unroll
    for (int j = 0; j < 32; j += 8)
        t[ty + j][tx] = in[(size_t)(r0 + ty + j) * ldin + c0 + tx];
    __syncthreads();
#pragma unroll
    for (int j = 0; j < 32; j += 8)
        out[(size_t)(c0 + ty + j) * ldout + r0 + tx] = t[tx][ty + j];
}

__global__ __launch_bounds__(256)
void cvt_split(const float* __restrict__ in, __hip_bfloat16* __restrict__ hi,
               __hip_bfloat16* __restrict__ lo)
{
    const int i = (blockIdx.x * 256 + threadIdx.x) * 4;
    f32x4 v = *(const f32x4*)(in + i);
#pragma unroll
    for (int k = 0; k < 4; ++k) {
        __hip_bfloat16 h = f2bf(v[k]);
        hi[i + k] = h;
        lo[i + k] = f2bf(v[k] - bf2f(h));
    }
}

// ---------------------------------------------------------------------------
// head tail: r = H2 @ Wh + bh (fp32; hi + optional lo), NIG transforms, opt G.
// ---------------------------------------------------------------------------
__global__ __launch_bounds__(256)
void head_tail(const __hip_bfloat16* __restrict__ H2hi, const __hip_bfloat16* __restrict__ H2lo,
               const float* __restrict__ Wh, const float* __restrict__ bh,
               const float* __restrict__ gamp,
               float* __restrict__ outBase, float* __restrict__ Gout)
{
    __shared__ float sa[64], sb[64];
    const int tid = threadIdx.x;
    const int rl  = tid >> 2;
    const int c   = tid & 3;
    const int row = blockIdx.x * 64 + rl;
    const __hip_bfloat16* hh = H2hi + (size_t)row * DH2;
    const __hip_bfloat16* hl = H2lo ? H2lo + (size_t)row * DH2 : nullptr;
    float acc = bh[c];
    if (hl) {
        for (int k = 0; k < DH2; ++k)
            acc = fmaf(bf2f(hh[k]) + bf2f(hl[k]), Wh[k * 4 + c], acc);
    } else {
        for (int k = 0; k < DH2; ++k)
            acc = fmaf(bf2f(hh[k]), Wh[k * 4 + c], acc);
    }
    float sp = softplus_f(acc);
    if (c == 0) {
        outBase[row] = acc;                        // mu
    } else if (c == 1) {
        outBase[NT + row] = sp + 1e-6f;            // v
    } else if (c == 2) {
        float a0 = (sp + 1.0f) + 1e-6f;            // match ref assoc order
        outBase[2 * NT + row] = a0;
        if (Gout) sa[rl] = a0 - 1.0f;
    } else {
        float b0 = sp + 1e-6f;
        outBase[3 * NT + row] = b0;
        if (Gout) sb[rl] = b0;
    }
    if (Gout != nullptr) {
        __syncthreads();
        if (c == 0) {
            float u   = sb[rl] / fmaxf(sa[rl], 1e-8f);
            float sig = 1.0f / (1.0f + expf(-u));
            Gout[row] = 1.0f - gamp[0] * sig;
        }
    }
}

// ---------------------------------------------------------------------------
extern "C" void kernel_launch(void* const* d_in, const int* in_sizes, int n_in,
                              void* d_out, int out_size, void* d_ws, size_t ws_size,
                              hipStream_t stream)
{
    (void)in_sizes; (void)n_in; (void)out_size; (void)ws_size;
    const float* X   = (const float*)d_in[0];
    const float* Wq  = (const float*)d_in[1];
    const float* Wk  = (const float*)d_in[2];
    const float* Wg  = (const float*)d_in[3];
    const float* bg  = (const float*)d_in[4];
    const float* gam = (const float*)d_in[5];
    const float* iW1 = (const float*)d_in[6];
    const float* ib1 = (const float*)d_in[7];
    const float* iW2 = (const float*)d_in[8];
    const float* ib2 = (const float*)d_in[9];
    const float* iWh = (const float*)d_in[10];
    const float* ibh = (const float*)d_in[11];
    const float* fW1 = (const float*)d_in[12];
    const float* fb1 = (const float*)d_in[13];
    const float* fW2 = (const float*)d_in[14];
    const float* fb2 = (const float*)d_in[15];
    const float* fWh = (const float*)d_in[16];
    const float* fbh = (const float*)d_in[17];
    float* out = (float*)d_out;

    char* cur = (char*)d_ws;
    auto alloc = [&](size_t bytes) -> char* {
        char* p = cur;
        cur += (bytes + 255) & ~(size_t)255;
        return p;
    };
    typedef __hip_bfloat16 bf;

    // Region A (64 MB): full Wp fp8 (8192x8192) aliased over buffers that are
    // dead during the attention phase (Xhi/Xlo/H1*/H2*).
    char* regA = alloc((size_t)NT * NT);
    uint8_t* Wp = (uint8_t*)regA;
    bf* Xhi  = (bf*)(regA);
    bf* Xlo  = (bf*)(regA + (size_t)NT * DD * 2);
    bf* H1hi = (bf*)(regA + (size_t)NT * DD * 4);
    bf* H1lo = (bf*)(regA + (size_t)NT * DD * 4 + (size_t)NT * DH1 * 2);
    bf* H2hi = (bf*)(regA + (size_t)NT * DD * 4 + (size_t)NT * DH1 * 4);
    bf* H2lo = (bf*)(regA + (size_t)NT * DD * 4 + (size_t)NT * DH1 * 4 + (size_t)NT * DH2 * 2);

    bf* WqkvT  = (bf*)alloc((size_t)3 * DD * DD * 2);
    bf* iW1hiT = (bf*)alloc((size_t)DH1 * DD * 2);
    bf* iW1loT = (bf*)alloc((size_t)DH1 * DD * 2);
    bf* iW2hiT = (bf*)alloc((size_t)DH2 * DH1 * 2);
    bf* iW2loT = (bf*)alloc((size_t)DH2 * DH1 * 2);
    bf* fW1hiT = (bf*)alloc((size_t)DH1 * DD * 2);
    bf* fW2hiT = (bf*)alloc((size_t)DH2 * DH1 * 2);
    uint8_t* QKVf8 = (uint8_t*)alloc((size_t)NT * 3 * DD);   // 8192 x 2304 fp8
    uint8_t* VTf8  = (uint8_t*)alloc((size_t)DD * NT);       // 768 x 8192 fp8
    float* G    = (float*)alloc((size_t)NT * 4);
    float* E    = (float*)alloc((size_t)NT * 4);
    float* T    = (float*)alloc((size_t)NT * 4);
    bf* Yhi    = (bf*)alloc((size_t)NT * DD * 2);

    const dim3 blk(256);

    // 1. converts / transposes
    cvt_split<<<dim3(NT * DD / 1024), blk, 0, stream>>>(X, Xhi, Xlo);
    transpose_f2b<<<dim3(DD / 32, DD / 32), blk, 0, stream>>>(Wq, DD, WqkvT, nullptr, DD);
    transpose_f2b<<<dim3(DD / 32, DD / 32), blk, 0, stream>>>(Wk, DD, WqkvT + (size_t)DD * DD, nullptr, DD);
    transpose_f2b<<<dim3(DD / 32, DD / 32), blk, 0, stream>>>(Wg, DD, WqkvT + (size_t)2 * DD * DD, nullptr, DD);
    transpose_f2b<<<dim3(DH1 / 32, DD / 32), blk, 0, stream>>>(iW1, DH1, iW1hiT, iW1loT, DD);
    transpose_f2b<<<dim3(DH2 / 32, DH1 / 32), blk, 0, stream>>>(iW2, DH2, iW2hiT, iW2loT, DH1);
    transpose_f2b<<<dim3(DH1 / 32, DD / 32), blk, 0, stream>>>(fW1, DH1, fW1hiT, nullptr, DD);
    transpose_f2b<<<dim3(DH2 / 32, DH1 / 32), blk, 0, stream>>>(fW2, DH2, fW2hiT, nullptr, DH1);

    // 2. head 1 (split-bf16 — G-cliff precision)
    gemm_bt<1, true, 64, 64><<<dim3(DH1 / 64, NT / 64), blk, 0, stream>>>(
        Xhi, Xlo, DD, iW1hiT, iW1loT, DD, H1hi, H1lo, nullptr, DH1, ib1, DD);
    gemm_bt<1, true, 64, 64><<<dim3(DH2 / 64, NT / 64), blk, 0, stream>>>(
        H1hi, H1lo, DH1, iW2hiT, iW2loT, DH1, H2hi, H2lo, nullptr, DH2, ib2, DH1);
    head_tail<<<dim3(NT / 64), blk, 0, stream>>>(H2hi, H2lo, iWh, ibh, gam, out, G);

    // 3. QKV projection -> fp8 directly (last reader of Xhi)
    gemm_bt<0, false, 128, 128><<<dim3(3 * DD / 128, NT / 128), blk, 0, stream>>>(
        Xhi, nullptr, DD, WqkvT, nullptr, DD, nullptr, nullptr, QKVf8, 3 * DD,
        nullptr, DD);
    transpose_f8<<<dim3(DD / 32, NT / 32), blk, 0, stream>>>(QKVf8 + 2 * DD, 3 * DD, VTf8, NT);

    hipMemsetAsync(E, 0, (size_t)NT * 4, stream);
    hipMemsetAsync(T, 0, (size_t)NT * 4, stream);

    // 4a. scores: Wp = exp(QK^T/sqrt(D))*G_j (full 8192x8192, fp8) + E/T sums.
    //     Wp clobbers region A (Xhi/Xlo/H1*/H2* all dead here).
    gemm_f8<2, 128, 128><<<dim3(NT / 128, NT / 128), blk, 0, stream>>>(
        QKVf8, 3 * DD, QKVf8 + DD, 3 * DD, Wp, NT,
        G, E, T, nullptr, nullptr, nullptr, nullptr, nullptr, nullptr, DD);

    // 4b. PV with fused Y epilogue: Y = X + gelu(alpha*(Wp@V) + bg).
    //     K=8192 -> 128-iter loop. E/T complete (4a finished).
    gemm_f8<4, 128, 64><<<dim3(DD / 64, NT / 128), blk, 0, stream>>>(
        Wp, NT, VTf8, NT, nullptr, DD,
        nullptr, nullptr, nullptr, X, bg, G, E, T, Yhi, NT);

    // 5. head 2 — plain bf16 (smooth outputs, ample threshold margin)
    gemm_bt<1, false, 64, 64><<<dim3(DH1 / 64, NT / 64), blk, 0, stream>>>(
        Yhi, nullptr, DD, fW1hiT, nullptr, DD, H1hi, nullptr, nullptr, DH1, fb1, DD);
    gemm_bt<1, false, 64, 64><<<dim3(DH2 / 64, NT / 64), blk, 0, stream>>>(
        H1hi, nullptr, DH1, fW2hiT, nullptr, DH1, H2hi, nullptr, nullptr, DH2, fb2, DH1);
    head_tail<<<dim3(NT / 64), blk, 0, stream>>>(H2hi, nullptr, fWh, fbh, gam, out + 4 * NT, nullptr);
}

// Round 9
// 548.607 us; speedup vs baseline: 1.3361x; 1.0036x over previous
//
#include <hip/hip_runtime.h>
#include <hip/hip_bf16.h>
#include <hip/hip_fp8.h>
#include <math.h>
#include <stdint.h>
#include <stddef.h>

// ---------------------------------------------------------------------------
// MetaEvidentialGSL: N=8192, D=768, H1=512, H2=256
// R2: XOR swizzle -> 0 conflicts. R4: dbuf + raw vmcnt barrier. R5: XCD
// remap. R6: head2 plain bf16. R7: fp8 attention. R8: full Wp + fused-Y PV.
// R9: scores split back to 2xN=4096 (B panel 3.1 MB fits 4 MiB XCD L2 --
//     R8's merged dispatch streamed 6.3 MB B from L3, FETCH 184 MB);
//     PV tile 64x64 (1536 blocks = 6/CU residency vs 3 -- grid was the cap).
// ---------------------------------------------------------------------------

#define NT    8192
#define DD    768
#define DH1   512
#define DH2   256
#define SPAN  4096   // scores N-split

typedef __attribute__((ext_vector_type(8))) short  short8;
typedef __attribute__((ext_vector_type(4))) float  f32x4;
typedef __attribute__((ext_vector_type(2))) long   longx2;

#define MFMA16(a, b, c) __builtin_amdgcn_mfma_f32_16x16x32_bf16((a), (b), (c), 0, 0, 0)
#define MFMAF8(a, b, c) __builtin_amdgcn_mfma_f32_16x16x32_fp8_fp8((a), (b), (c), 0, 0, 0)

__device__ __forceinline__ float bf2f(__hip_bfloat16 x) { return __bfloat162float(x); }
__device__ __forceinline__ __hip_bfloat16 f2bf(float x) { return __float2bfloat16(x); }
__device__ __forceinline__ uint8_t f2fp8(float x) { return __hip_fp8_e4m3(x).__x; }

__device__ __forceinline__ float gelu_f(float x) {
    return 0.5f * x * (1.0f + erff(x * 0.7071067811865476f));
}
__device__ __forceinline__ float softplus_f(float x) {
    return (x > 20.0f) ? x : log1pf(expf(x));
}

// async 16B/lane global->LDS. LDS dest must be wave-uniform base + lane*16.
__device__ __forceinline__ void gload16(const void* g, void* l) {
    __builtin_amdgcn_global_load_lds(
        (const __attribute__((address_space(1))) void*)g,
        (__attribute__((address_space(3))) void*)l, 16, 0, 0);
}

// wait until <=N vm ops outstanding, then barrier.
template <int N>
__device__ __forceinline__ void wait_barrier() {
    asm volatile("s_waitcnt vmcnt(%0)\n\ts_barrier" :: "i"(N) : "memory");
}
__device__ __forceinline__ void plain_barrier() {
    asm volatile("s_barrier" ::: "memory");
}

// XCD-aware remap: linear workgroup id round-robins across 8 XCDs (id % 8).
__device__ __forceinline__ void xcd_remap(int& bx, int& by) {
    const int nbx = gridDim.x, nby = gridDim.y;
    if ((nby & 7) == 0) {
        const int lin = by * nbx + bx;
        const int x   = lin & 7;
        const int s   = lin >> 3;
        bx = s % nbx;
        by = x + 8 * (s / nbx);
    }
}

// ---------------------------------------------------------------------------
// bf16 GEMM (heads + QKV): C(MxN) = A @ Bt^T. BK=32, double-buffered.
// EPI: 0 = store bf16 (obf_hi) and/or fp8 (of8); 1 = bias+gelu -> bf16 (+lo)
// ---------------------------------------------------------------------------
template <int EPI, bool SPLIT, int TM, int TN>
__global__ __launch_bounds__(256)
void gemm_bt(const __hip_bfloat16* __restrict__ Ahi, const __hip_bfloat16* __restrict__ Alo, int lda,
             const __hip_bfloat16* __restrict__ Bhi, const __hip_bfloat16* __restrict__ Blo, int ldb,
             __hip_bfloat16* __restrict__ obf_hi, __hip_bfloat16* __restrict__ obf_lo,
             uint8_t* __restrict__ of8, int ldc,
             const float* __restrict__ bias, int K)
{
    constexpr int NB  = SPLIT ? 2 : 1;
    constexpr int WRM = (TM == 128 && TN == 128) ? 2 : (TM == 128 ? 4 : 2);
    constexpr int WCN = 4 / WRM;
    constexpr int WTM = TM / WRM;
    constexpr int WTN = TN / WCN;
    constexpr int MI  = WTM / 16;
    constexpr int NI  = WTN / 16;
    constexpr int PA  = TM / 64;
    constexpr int PB  = TN / 64;
    constexpr int LPI = (PA + PB) * NB;

    __shared__ __align__(16) __hip_bfloat16 As[NB][2][TM * 32];
    __shared__ __align__(16) __hip_bfloat16 Bs[NB][2][TN * 32];

    const int tid  = threadIdx.x;
    const int wave = tid >> 6;
    const int lane = tid & 63;
    int bx = blockIdx.x, by = blockIdx.y;
    xcd_remap(bx, by);
    const int tm = by * TM;
    const int tn = bx * TN;

    const int srow  = tid >> 2;
    const int sgcol = ((tid & 3) ^ ((srow >> 1) & 3)) * 8;
    const int lofs  = srow * 32 + (tid & 3) * 8;

    size_t aoffs[PA], boffs[PB];
#pragma unroll
    for (int p = 0; p < PA; ++p) aoffs[p] = (size_t)(tm + p * 64 + srow) * lda + sgcol;
#pragma unroll
    for (int p = 0; p < PB; ++p) boffs[p] = (size_t)(tn + p * 64 + srow) * ldb + sgcol;

    auto stage = [&](int k0, int buf) {
#pragma unroll
        for (int p = 0; p < PA; ++p)
            gload16(Ahi + aoffs[p] + k0, &As[0][buf][p * 2048 + lofs]);
#pragma unroll
        for (int p = 0; p < PB; ++p)
            gload16(Bhi + boffs[p] + k0, &Bs[0][buf][p * 2048 + lofs]);
        if constexpr (SPLIT) {
#pragma unroll
            for (int p = 0; p < PA; ++p)
                gload16(Alo + aoffs[p] + k0, &As[1][buf][p * 2048 + lofs]);
#pragma unroll
            for (int p = 0; p < PB; ++p)
                gload16(Blo + boffs[p] + k0, &Bs[1][buf][p * 2048 + lofs]);
        }
    };

    f32x4 acc[MI][NI];
#pragma unroll
    for (int i = 0; i < MI; ++i)
#pragma unroll
        for (int j = 0; j < NI; ++j) {
            f32x4 z = {0.0f, 0.0f, 0.0f, 0.0f};
            acc[i][j] = z;
        }

    const int wm   = (wave / WCN) * WTM;
    const int wn   = (wave % WCN) * WTN;
    const int l16  = lane & 15;
    const int quad = lane >> 4;
    const int rchunk = (quad ^ ((l16 >> 1) & 3)) * 8;
    const int arow0  = (wm + l16) * 32 + rchunk;
    const int brow0  = (wn + l16) * 32 + rchunk;

    const int nIter = K >> 5;
    stage(0, 0);
    for (int k = 0; k < nIter; ++k) {
        const int cb = k & 1;
        if (k + 1 < nIter) {
            stage((k + 1) << 5, cb ^ 1);
            wait_barrier<LPI>();
        } else {
            wait_barrier<0>();
        }

        short8 ah[MI], bh[NI];
#pragma unroll
        for (int i = 0; i < MI; ++i) ah[i] = *(const short8*)&As[0][cb][arow0 + i * 512];
#pragma unroll
        for (int j = 0; j < NI; ++j) bh[j] = *(const short8*)&Bs[0][cb][brow0 + j * 512];
        if constexpr (SPLIT) {
            short8 al[MI], bl[NI];
#pragma unroll
            for (int i = 0; i < MI; ++i) al[i] = *(const short8*)&As[1][cb][arow0 + i * 512];
#pragma unroll
            for (int j = 0; j < NI; ++j) bl[j] = *(const short8*)&Bs[1][cb][brow0 + j * 512];
#pragma unroll
            for (int mi = 0; mi < MI; ++mi)
#pragma unroll
                for (int ni = 0; ni < NI; ++ni) {
                    acc[mi][ni] = MFMA16(ah[mi], bh[ni], acc[mi][ni]);
                    acc[mi][ni] = MFMA16(ah[mi], bl[ni], acc[mi][ni]);
                    acc[mi][ni] = MFMA16(al[mi], bh[ni], acc[mi][ni]);
                }
        } else {
#pragma unroll
            for (int mi = 0; mi < MI; ++mi)
#pragma unroll
                for (int ni = 0; ni < NI; ++ni)
                    acc[mi][ni] = MFMA16(ah[mi], bh[ni], acc[mi][ni]);
        }
        plain_barrier();
    }

    // C/D layout: col = lane&15, row = (lane>>4)*4 + reg  [verified m89/m91]
    const int rbase = tm + wm + quad * 4;
    const int cbase = tn + wn + l16;

    if constexpr (EPI == 0) {
#pragma unroll
        for (int mi = 0; mi < MI; ++mi)
#pragma unroll
            for (int ni = 0; ni < NI; ++ni) {
                f32x4 v = acc[mi][ni];
                const int col = cbase + ni * 16;
#pragma unroll
                for (int r = 0; r < 4; ++r) {
                    size_t idx = (size_t)(rbase + mi * 16 + r) * ldc + col;
                    if (obf_hi) obf_hi[idx] = f2bf(v[r]);
                    if (of8)    of8[idx]    = f2fp8(v[r]);
                }
            }
    } else {  // EPI == 1
#pragma unroll
        for (int mi = 0; mi < MI; ++mi)
#pragma unroll
            for (int ni = 0; ni < NI; ++ni) {
                f32x4 v = acc[mi][ni];
                const int col = cbase + ni * 16;
                const float b = bias[col];
#pragma unroll
                for (int r = 0; r < 4; ++r) {
                    float g = gelu_f(v[r] + b);
                    __hip_bfloat16 h = f2bf(g);
                    size_t idx = (size_t)(rbase + mi * 16 + r) * ldc + col;
                    obf_hi[idx] = h;
                    if (obf_lo) obf_lo[idx] = f2bf(g - bf2f(h));
                }
            }
    }
}

// ---------------------------------------------------------------------------
// fp8 GEMM (attention): C(MxN) = A(MxK) @ Bt(NxK)^T, fp8 e4m3 inputs.
// BK=64, double-buffered, byte-level XOR swizzle (0 conflicts).
// EPI: 2 = w=exp(acc/sqrt(D))*G[col] -> fp8, atomic rowsum E (exp) / T (w)
//      4 = fused Y epilogue: Y = X + gelu(alpha*acc + bg),
//          alpha = G/(E*max(G*T/E,1e-8))   (exact reference clamp semantics)
// ---------------------------------------------------------------------------
template <int EPI, int TM, int TN>
__global__ __launch_bounds__(256)
void gemm_f8(const uint8_t* __restrict__ A, int lda,
             const uint8_t* __restrict__ B, int ldb,
             uint8_t* __restrict__ of8, int ldc,
             const float* __restrict__ Gv, float* __restrict__ Esum,
             float* __restrict__ Tsum,
             const float* __restrict__ Xf, const float* __restrict__ bg2,
             const float* __restrict__ Grow, const float* __restrict__ Erow,
             const float* __restrict__ Trow,
             __hip_bfloat16* __restrict__ Yout, int K)
{
    constexpr int WRM = (TM == 128 && TN == 128) ? 2 : (TM == 128 ? 4 : 2);
    constexpr int WCN = 4 / WRM;
    constexpr int WTM = TM / WRM;
    constexpr int WTN = TN / WCN;
    constexpr int MI  = WTM / 16;
    constexpr int NI  = WTN / 16;
    constexpr int PA  = TM / 64;
    constexpr int PB  = TN / 64;
    constexpr int LPI = PA + PB;

    __shared__ __align__(16) uint8_t As[2][TM * 64];
    __shared__ __align__(16) uint8_t Bs[2][TN * 64];

    const int tid  = threadIdx.x;
    const int wave = tid >> 6;
    const int lane = tid & 63;
    int bx = blockIdx.x, by = blockIdx.y;
    xcd_remap(bx, by);
    const int tm = by * TM;
    const int tn = bx * TN;

    const int srow  = tid >> 2;
    const int sgcol = ((tid & 3) ^ ((srow >> 1) & 3)) * 16;   // byte col
    const int lofs  = tid * 16;

    size_t aoffs[PA], boffs[PB];
#pragma unroll
    for (int p = 0; p < PA; ++p) aoffs[p] = (size_t)(tm + p * 64 + srow) * lda + sgcol;
#pragma unroll
    for (int p = 0; p < PB; ++p) boffs[p] = (size_t)(tn + p * 64 + srow) * ldb + sgcol;

    auto stage = [&](int k0, int buf) {
#pragma unroll
        for (int p = 0; p < PA; ++p)
            gload16(A + aoffs[p] + k0, &As[buf][p * 4096 + lofs]);
#pragma unroll
        for (int p = 0; p < PB; ++p)
            gload16(B + boffs[p] + k0, &Bs[buf][p * 4096 + lofs]);
    };

    f32x4 acc[MI][NI];
#pragma unroll
    for (int i = 0; i < MI; ++i)
#pragma unroll
        for (int j = 0; j < NI; ++j) {
            f32x4 z = {0.0f, 0.0f, 0.0f, 0.0f};
            acc[i][j] = z;
        }

    const int wm   = (wave / WCN) * WTM;
    const int wn   = (wave % WCN) * WTN;
    const int l16  = lane & 15;
    const int quad = lane >> 4;
    const int rchunk = (quad ^ ((l16 >> 1) & 3)) * 16;
    const int arow0  = (wm + l16) * 64 + rchunk;
    const int brow0  = (wn + l16) * 64 + rchunk;

    const int nIter = K >> 6;
    stage(0, 0);
    for (int k = 0; k < nIter; ++k) {
        const int cb = k & 1;
        if (k + 1 < nIter) {
            stage((k + 1) << 6, cb ^ 1);
            wait_barrier<LPI>();
        } else {
            wait_barrier<0>();
        }

        longx2 a[MI], b[NI];
#pragma unroll
        for (int i = 0; i < MI; ++i) a[i] = *(const longx2*)&As[cb][arow0 + i * 1024];
#pragma unroll
        for (int j = 0; j < NI; ++j) b[j] = *(const longx2*)&Bs[cb][brow0 + j * 1024];
#pragma unroll
        for (int mi = 0; mi < MI; ++mi)
#pragma unroll
            for (int ni = 0; ni < NI; ++ni) {
                acc[mi][ni] = MFMAF8(a[mi][0], b[ni][0], acc[mi][ni]);
                acc[mi][ni] = MFMAF8(a[mi][1], b[ni][1], acc[mi][ni]);
            }
        plain_barrier();
    }

    const int rbase = tm + wm + quad * 4;
    const int cbase = tn + wn + l16;

    if constexpr (EPI == 2) {
        const float SCL = 0.03608439182435161f;   // 1/sqrt(768)
#pragma unroll
        for (int mi = 0; mi < MI; ++mi) {
            float sE[4] = {0.f, 0.f, 0.f, 0.f};
            float sT[4] = {0.f, 0.f, 0.f, 0.f};
#pragma unroll
            for (int ni = 0; ni < NI; ++ni) {
                f32x4 v = acc[mi][ni];
                const int col = cbase + ni * 16;
                const float g = Gv[col];
#pragma unroll
                for (int r = 0; r < 4; ++r) {
                    float we = __expf(v[r] * SCL);
                    float w  = we * g;
                    of8[(size_t)(rbase + mi * 16 + r) * ldc + col] = f2fp8(w);
                    sE[r] += we;
                    sT[r] += w;
                }
            }
#pragma unroll
            for (int st = 1; st < 16; st <<= 1)
#pragma unroll
                for (int r = 0; r < 4; ++r) {
                    sE[r] += __shfl_xor(sE[r], st);
                    sT[r] += __shfl_xor(sT[r], st);
                }
            if (l16 == 0) {
#pragma unroll
                for (int r = 0; r < 4; ++r) {
                    atomicAdd(&Esum[rbase + mi * 16 + r], sE[r]);
                    atomicAdd(&Tsum[rbase + mi * 16 + r], sT[r]);
                }
            }
        }
    } else {  // EPI == 4: fused Y = X + gelu(alpha*acc + bg)
#pragma unroll
        for (int mi = 0; mi < MI; ++mi) {
#pragma unroll
            for (int r = 0; r < 4; ++r) {
                const int row = rbase + mi * 16 + r;
                const float g = Grow[row], e = Erow[row], t = Trow[row];
                const float denom = fmaxf(g * t / e, 1e-8f);
                const float alpha = g / (e * denom);
#pragma unroll
                for (int ni = 0; ni < NI; ++ni) {
                    const int col = cbase + ni * 16;
                    const float m = alpha * acc[mi][ni][r];
                    const size_t idx = (size_t)row * ldc + col;
                    Yout[idx] = f2bf(Xf[idx] + gelu_f(m + bg2[col]));
                }
            }
        }
    }
}

// ---------------------------------------------------------------------------
__global__ __launch_bounds__(256)
void transpose_f2b(const float* __restrict__ in, int ldin,
                   __hip_bfloat16* __restrict__ ohi, __hip_bfloat16* __restrict__ olo, int ldout)
{
    __shared__ float t[32][33];
    const int tx = threadIdx.x & 31;
    const int ty = threadIdx.x >> 5;
    const int r0 = blockIdx.y * 32;
    const int c0 = blockIdx.x * 32;
#pragma unroll
    for (int j = 0; j < 32; j += 8)
        t[ty + j][tx] = in[(size_t)(r0 + ty + j) * ldin + c0 + tx];
    __syncthreads();
#pragma unroll
    for (int j = 0; j < 32; j += 8) {
        float x = t[tx][ty + j];
        __hip_bfloat16 h = f2bf(x);
        size_t o = (size_t)(c0 + ty + j) * ldout + r0 + tx;
        ohi[o] = h;
        if (olo) olo[o] = f2bf(x - bf2f(h));
    }
}

// fp8 byte transpose (V part of QKVf8 -> VTf8)
__global__ __launch_bounds__(256)
void transpose_f8(const uint8_t* __restrict__ in, int ldin,
                  uint8_t* __restrict__ out, int ldout)
{
    __shared__ uint8_t t[32][33];
    const int tx = threadIdx.x & 31;
    const int ty = threadIdx.x >> 5;
    const int r0 = blockIdx.y * 32;
    const int c0 = blockIdx.x * 32;
#pragma unroll
    for (int j = 0; j < 32; j += 8)
        t[ty + j][tx] = in[(size_t)(r0 + ty + j) * ldin + c0 + tx];
    __syncthreads();
#pragma unroll
    for (int j = 0; j < 32; j += 8)
        out[(size_t)(c0 + ty + j) * ldout + r0 + tx] = t[tx][ty + j];
}

__global__ __launch_bounds__(256)
void cvt_split(const float* __restrict__ in, __hip_bfloat16* __restrict__ hi,
               __hip_bfloat16* __restrict__ lo)
{
    const int i = (blockIdx.x * 256 + threadIdx.x) * 4;
    f32x4 v = *(const f32x4*)(in + i);
#pragma unroll
    for (int k = 0; k < 4; ++k) {
        __hip_bfloat16 h = f2bf(v[k]);
        hi[i + k] = h;
        lo[i + k] = f2bf(v[k] - bf2f(h));
    }
}

// ---------------------------------------------------------------------------
// head tail: r = H2 @ Wh + bh (fp32; hi + optional lo), NIG transforms, opt G.
// ---------------------------------------------------------------------------
__global__ __launch_bounds__(256)
void head_tail(const __hip_bfloat16* __restrict__ H2hi, const __hip_bfloat16* __restrict__ H2lo,
               const float* __restrict__ Wh, const float* __restrict__ bh,
               const float* __restrict__ gamp,
               float* __restrict__ outBase, float* __restrict__ Gout)
{
    __shared__ float sa[64], sb[64];
    const int tid = threadIdx.x;
    const int rl  = tid >> 2;
    const int c   = tid & 3;
    const int row = blockIdx.x * 64 + rl;
    const __hip_bfloat16* hh = H2hi + (size_t)row * DH2;
    const __hip_bfloat16* hl = H2lo ? H2lo + (size_t)row * DH2 : nullptr;
    float acc = bh[c];
    if (hl) {
        for (int k = 0; k < DH2; ++k)
            acc = fmaf(bf2f(hh[k]) + bf2f(hl[k]), Wh[k * 4 + c], acc);
    } else {
        for (int k = 0; k < DH2; ++k)
            acc = fmaf(bf2f(hh[k]), Wh[k * 4 + c], acc);
    }
    float sp = softplus_f(acc);
    if (c == 0) {
        outBase[row] = acc;                        // mu
    } else if (c == 1) {
        outBase[NT + row] = sp + 1e-6f;            // v
    } else if (c == 2) {
        float a0 = (sp + 1.0f) + 1e-6f;            // match ref assoc order
        outBase[2 * NT + row] = a0;
        if (Gout) sa[rl] = a0 - 1.0f;
    } else {
        float b0 = sp + 1e-6f;
        outBase[3 * NT + row] = b0;
        if (Gout) sb[rl] = b0;
    }
    if (Gout != nullptr) {
        __syncthreads();
        if (c == 0) {
            float u   = sb[rl] / fmaxf(sa[rl], 1e-8f);
            float sig = 1.0f / (1.0f + expf(-u));
            Gout[row] = 1.0f - gamp[0] * sig;
        }
    }
}

// ---------------------------------------------------------------------------
extern "C" void kernel_launch(void* const* d_in, const int* in_sizes, int n_in,
                              void* d_out, int out_size, void* d_ws, size_t ws_size,
                              hipStream_t stream)
{
    (void)in_sizes; (void)n_in; (void)out_size; (void)ws_size;
    const float* X   = (const float*)d_in[0];
    const float* Wq  = (const float*)d_in[1];
    const float* Wk  = (const float*)d_in[2];
    const float* Wg  = (const float*)d_in[3];
    const float* bg  = (const float*)d_in[4];
    const float* gam = (const float*)d_in[5];
    const float* iW1 = (const float*)d_in[6];
    const float* ib1 = (const float*)d_in[7];
    const float* iW2 = (const float*)d_in[8];
    const float* ib2 = (const float*)d_in[9];
    const float* iWh = (const float*)d_in[10];
    const float* ibh = (const float*)d_in[11];
    const float* fW1 = (const float*)d_in[12];
    const float* fb1 = (const float*)d_in[13];
    const float* fW2 = (const float*)d_in[14];
    const float* fb2 = (const float*)d_in[15];
    const float* fWh = (const float*)d_in[16];
    const float* fbh = (const float*)d_in[17];
    float* out = (float*)d_out;

    char* cur = (char*)d_ws;
    auto alloc = [&](size_t bytes) -> char* {
        char* p = cur;
        cur += (bytes + 255) & ~(size_t)255;
        return p;
    };
    typedef __hip_bfloat16 bf;

    // Region A (64 MB): full Wp fp8 (8192x8192) aliased over buffers that are
    // dead during the attention phase (Xhi/Xlo/H1*/H2*).
    char* regA = alloc((size_t)NT * NT);
    uint8_t* Wp = (uint8_t*)regA;
    bf* Xhi  = (bf*)(regA);
    bf* Xlo  = (bf*)(regA + (size_t)NT * DD * 2);
    bf* H1hi = (bf*)(regA + (size_t)NT * DD * 4);
    bf* H1lo = (bf*)(regA + (size_t)NT * DD * 4 + (size_t)NT * DH1 * 2);
    bf* H2hi = (bf*)(regA + (size_t)NT * DD * 4 + (size_t)NT * DH1 * 4);
    bf* H2lo = (bf*)(regA + (size_t)NT * DD * 4 + (size_t)NT * DH1 * 4 + (size_t)NT * DH2 * 2);

    bf* WqkvT  = (bf*)alloc((size_t)3 * DD * DD * 2);
    bf* iW1hiT = (bf*)alloc((size_t)DH1 * DD * 2);
    bf* iW1loT = (bf*)alloc((size_t)DH1 * DD * 2);
    bf* iW2hiT = (bf*)alloc((size_t)DH2 * DH1 * 2);
    bf* iW2loT = (bf*)alloc((size_t)DH2 * DH1 * 2);
    bf* fW1hiT = (bf*)alloc((size_t)DH1 * DD * 2);
    bf* fW2hiT = (bf*)alloc((size_t)DH2 * DH1 * 2);
    uint8_t* QKVf8 = (uint8_t*)alloc((size_t)NT * 3 * DD);   // 8192 x 2304 fp8
    uint8_t* VTf8  = (uint8_t*)alloc((size_t)DD * NT);       // 768 x 8192 fp8
    float* G    = (float*)alloc((size_t)NT * 4);
    float* E    = (float*)alloc((size_t)NT * 4);
    float* T    = (float*)alloc((size_t)NT * 4);
    bf* Yhi    = (bf*)alloc((size_t)NT * DD * 2);

    const dim3 blk(256);

    // 1. converts / transposes
    cvt_split<<<dim3(NT * DD / 1024), blk, 0, stream>>>(X, Xhi, Xlo);
    transpose_f2b<<<dim3(DD / 32, DD / 32), blk, 0, stream>>>(Wq, DD, WqkvT, nullptr, DD);
    transpose_f2b<<<dim3(DD / 32, DD / 32), blk, 0, stream>>>(Wk, DD, WqkvT + (size_t)DD * DD, nullptr, DD);
    transpose_f2b<<<dim3(DD / 32, DD / 32), blk, 0, stream>>>(Wg, DD, WqkvT + (size_t)2 * DD * DD, nullptr, DD);
    transpose_f2b<<<dim3(DH1 / 32, DD / 32), blk, 0, stream>>>(iW1, DH1, iW1hiT, iW1loT, DD);
    transpose_f2b<<<dim3(DH2 / 32, DH1 / 32), blk, 0, stream>>>(iW2, DH2, iW2hiT, iW2loT, DH1);
    transpose_f2b<<<dim3(DH1 / 32, DD / 32), blk, 0, stream>>>(fW1, DH1, fW1hiT, nullptr, DD);
    transpose_f2b<<<dim3(DH2 / 32, DH1 / 32), blk, 0, stream>>>(fW2, DH2, fW2hiT, nullptr, DH1);

    // 2. head 1 (split-bf16 — G-cliff precision)
    gemm_bt<1, true, 64, 64><<<dim3(DH1 / 64, NT / 64), blk, 0, stream>>>(
        Xhi, Xlo, DD, iW1hiT, iW1loT, DD, H1hi, H1lo, nullptr, DH1, ib1, DD);
    gemm_bt<1, true, 64, 64><<<dim3(DH2 / 64, NT / 64), blk, 0, stream>>>(
        H1hi, H1lo, DH1, iW2hiT, iW2loT, DH1, H2hi, H2lo, nullptr, DH2, ib2, DH1);
    head_tail<<<dim3(NT / 64), blk, 0, stream>>>(H2hi, H2lo, iWh, ibh, gam, out, G);

    // 3. QKV projection -> fp8 directly (last reader of Xhi)
    gemm_bt<0, false, 128, 128><<<dim3(3 * DD / 128, NT / 128), blk, 0, stream>>>(
        Xhi, nullptr, DD, WqkvT, nullptr, DD, nullptr, nullptr, QKVf8, 3 * DD,
        nullptr, DD);
    transpose_f8<<<dim3(DD / 32, NT / 32), blk, 0, stream>>>(QKVf8 + 2 * DD, 3 * DD, VTf8, NT);

    hipMemsetAsync(E, 0, (size_t)NT * 4, stream);
    hipMemsetAsync(T, 0, (size_t)NT * 4, stream);

    // 4a. scores in two N=4096 dispatches (K panel 3.1 MB stays L2-resident
    //     per XCD). Both write the full Wp; Wp clobbers region A (dead bufs).
    for (int p = 0; p < 2; ++p) {
        const uint8_t* Kp = QKVf8 + (size_t)p * SPAN * (3 * DD) + DD;
        gemm_f8<2, 128, 128><<<dim3(SPAN / 128, NT / 128), blk, 0, stream>>>(
            QKVf8, 3 * DD, Kp, 3 * DD, Wp + (size_t)p * SPAN, NT,
            G + p * SPAN, E, T, nullptr, nullptr, nullptr, nullptr, nullptr, nullptr, DD);
    }

    // 4b. PV with fused Y epilogue, 64x64 tiles (1536 blocks = 6/CU residency).
    gemm_f8<4, 64, 64><<<dim3(DD / 64, NT / 64), blk, 0, stream>>>(
        Wp, NT, VTf8, NT, nullptr, DD,
        nullptr, nullptr, nullptr, X, bg, G, E, T, Yhi, NT);

    // 5. head 2 — plain bf16 (smooth outputs, ample threshold margin)
    gemm_bt<1, false, 64, 64><<<dim3(DH1 / 64, NT / 64), blk, 0, stream>>>(
        Yhi, nullptr, DD, fW1hiT, nullptr, DD, H1hi, nullptr, nullptr, DH1, fb1, DD);
    gemm_bt<1, false, 64, 64><<<dim3(DH2 / 64, NT / 64), blk, 0, stream>>>(
        H1hi, nullptr, DH1, fW2hiT, nullptr, DH1, H2hi, nullptr, nullptr, DH2, fb2, DH1);
    head_tail<<<dim3(NT / 64), blk, 0, stream>>>(H2hi, nullptr, fWh, fbh, gam, out + 4 * NT, nullptr);
}